// Round 10
// baseline (234.922 us; speedup 1.0000x reference)
//
#include <hip/hip_runtime.h>
#include <hip/hip_bf16.h>

#define B_   32
#define D_   512
#define L_   49
#define E_   4
#define KD_  4
#define NS_  16
#define RK_  32
#define JOBS_ 64

typedef short s16x8 __attribute__((ext_vector_type(8)));
typedef float f32x4v __attribute__((ext_vector_type(4)));
union U4 { uint4 u; s16x8 s; unsigned short us[8]; };

// ---------- helpers ----------
__device__ __forceinline__ float bf2f(unsigned short u){
  union{unsigned int i; float f;} v; v.i = ((unsigned int)u)<<16; return v.f;
}
__device__ __forceinline__ float2 bfp(unsigned int u){
  union{unsigned int i; float f;} a, b; a.i = u<<16; b.i = u & 0xffff0000u;
  return make_float2(a.f, b.f);
}
__device__ __forceinline__ unsigned short f2bfu(float f){
  union{float f; unsigned int i;} u; u.f = f;
  unsigned int r = u.i + 0x7fffu + ((u.i >> 16) & 1u);
  return (unsigned short)(r >> 16);
}
__device__ __forceinline__ float silu_f(float x){ return x / (1.f + expf(-x)); }

// single v_exp_f32 via builtin (ocml exp2f carries range-fixup instrs; args here
// are <=0 and results match in the normal range; sub-denormal flushes to 0)
__device__ __forceinline__ float fast_exp2(float x){
  return __builtin_amdgcn_exp2f(x);
}
// quad butterfly add via mov_dpp (VALU pipe, not DS) — R4-proven form.
__device__ __forceinline__ float quad_add4(float y){
  float t1 = __uint_as_float(__builtin_amdgcn_mov_dpp(__float_as_uint(y), 0xB1, 0xF, 0xF, true));
  y += t1;
  float t2 = __uint_as_float(__builtin_amdgcn_mov_dpp(__float_as_uint(y), 0x4E, 0xF, 0xF, true));
  y += t2;
  return y;
}
// v_cvt_pk_bf16_f32: RNE pack of 2 f32 -> 2 bf16 in one u32 (== f2bfu semantics);
// guide-verified inline-asm recipe (no builtin exists on gfx950).
__device__ __forceinline__ unsigned cvtpk_bf16(float lo, float hi){
  unsigned r; asm("v_cvt_pk_bf16_f32 %0, %1, %2" : "=v"(r) : "v"(lo), "v"(hi)); return r;
}

// inline dtype detection: wave-ballot over x[0..63] viewed as bf16 (~5 instr).
__device__ __forceinline__ int detect_bf(const void* x){
  unsigned short u = ((const unsigned short*)x)[threadIdx.x & 63];
  int e = (u >> 7) & 0xff;
  unsigned long long m = __ballot(e >= 96 && e < 160);
  return __popcll(m) >= 56;
}

// dtype-agnostic loads: bf=1 -> bf16 (ushort), bf=0 -> float32
__device__ __forceinline__ float ldf(const void* p, size_t i, int bf){
  return bf ? bf2f(((const unsigned short*)p)[i]) : ((const float*)p)[i];
}
struct f8s{ float v[8]; };
__device__ __forceinline__ f8s ldf8(const void* p, size_t i, int bf){
  f8s r;
  if (bf){
    uint4 u = *(const uint4*)((const unsigned short*)p + i);
    float2 x = bfp(u.x), y = bfp(u.y), z = bfp(u.z), w = bfp(u.w);
    r.v[0]=x.x; r.v[1]=x.y; r.v[2]=y.x; r.v[3]=y.y;
    r.v[4]=z.x; r.v[5]=z.y; r.v[6]=w.x; r.v[7]=w.y;
  } else {
    const float4* q = (const float4*)((const float*)p + i);
    float4 a = q[0], b = q[1];
    r.v[0]=a.x; r.v[1]=a.y; r.v[2]=a.z; r.v[3]=a.w;
    r.v[4]=b.x; r.v[5]=b.y; r.v[6]=b.z; r.v[7]=b.w;
  }
  return r;
}
struct f4s{ float v[4]; };
__device__ __forceinline__ f4s ldf4(const void* p, size_t i, int bf){
  f4s r;
  if (bf){
    uint2 u = *(const uint2*)((const unsigned short*)p + i);
    float2 a = bfp(u.x), b = bfp(u.y);
    r.v[0]=a.x; r.v[1]=a.y; r.v[2]=b.x; r.v[3]=b.y;
  } else {
    float4 a = *(const float4*)((const float*)p + i);
    r.v[0]=a.x; r.v[1]=a.y; r.v[2]=a.z; r.v[3]=a.w;
  }
  return r;
}
// load 8 elems as bf16 frag (bf16: direct; fp32: convert)
__device__ __forceinline__ U4 ldbf8(const void* p, size_t i, int bf){
  U4 r;
  if (bf){
    r.u = *(const uint4*)((const unsigned short*)p + i);
  } else {
    const float* q = (const float*)p + i;
    float4 a = *(const float4*)q, b = *(const float4*)(q+4);
    r.u.x = (unsigned)f2bfu(a.x) | ((unsigned)f2bfu(a.y) << 16);
    r.u.y = (unsigned)f2bfu(a.z) | ((unsigned)f2bfu(a.w) << 16);
    r.u.z = (unsigned)f2bfu(b.x) | ((unsigned)f2bfu(b.y) << 16);
    r.u.w = (unsigned)f2bfu(b.z) | ((unsigned)f2bfu(b.w) << 16);
  }
  return r;
}
// split 8 fp32 into hi (truncated bf16) + lo (rounded residual bf16)
__device__ __forceinline__ void split8(const float av[8], U4& hi, U4& lo){
  #pragma unroll
  for (int j = 0; j < 8; j++){
    union{float f; unsigned int i;} u; u.f = av[j];
    unsigned short h = (unsigned short)(u.i >> 16);   // trunc — residual goes to lo
    hi.us[j] = h;
    lo.us[j] = f2bfu(av[j] - bf2f(h));
  }
}

// direction index map: xs[k,d,l] = xc[d, dirmap(k,l)]; all four maps are involutions.
__device__ __forceinline__ int dirmap(int k, int l){
  if (k == 0) return l;
  if (k == 1) return 48 - l;
  if (k == 2) return (l % 7) * 7 + l / 7;
  int l2 = 48 - l; return (l2 % 7) * 7 + l2 / 7;
}

// ---------- 1. k_prep: wtrans (blocks 0..511) + bgate logits + xbf (blocks 512..543) ----------
__global__ __launch_bounds__(256) void k_prep(const void* __restrict__ x,
                                              const void* __restrict__ w,
                                              const void* __restrict__ wg,
                                              const void* __restrict__ bg,
                                              unsigned short* __restrict__ wt,
                                              unsigned short* __restrict__ xbf,
                                              float* __restrict__ logits){
  __shared__ unsigned short tile[64][72];
  __shared__ float red[4][4];
  __shared__ float pool[4][512];
  int bf = detect_bf(x);
  int blk = blockIdx.x;
  int t = threadIdx.x;
  if (blk < 512){
    int e = blk >> 7, cb = (blk >> 3) & 15, db = blk & 7;
    #pragma unroll
    for (int r = 0; r < 4; r++){
      int d  = r*16 + (t>>4);
      int c0 = (t&15)*4;
      size_t g = ((size_t)e*512 + db*64 + d)*1024 + cb*64 + c0;
      if (bf){
        uint2 u = *(const uint2*)((const unsigned short*)w + g);
        tile[c0+0][d] = (unsigned short)(u.x & 0xffffu);
        tile[c0+1][d] = (unsigned short)(u.x >> 16);
        tile[c0+2][d] = (unsigned short)(u.y & 0xffffu);
        tile[c0+3][d] = (unsigned short)(u.y >> 16);
      } else {
        float4 v = *(const float4*)((const float*)w + g);
        tile[c0+0][d] = f2bfu(v.x);
        tile[c0+1][d] = f2bfu(v.y);
        tile[c0+2][d] = f2bfu(v.z);
        tile[c0+3][d] = f2bfu(v.w);
      }
    }
    __syncthreads();
    #pragma unroll
    for (int r = 0; r < 2; r++){
      int o = r*256 + t;
      int c = o >> 3, d0 = (o & 7)*8;
      uint4 v = *(const uint4*)&tile[c][d0];
      *(uint4*)(wt + ((size_t)e*1024 + cb*64 + c)*512 + db*64 + d0) = v;
    }
  } else {
    int b = blk - 512;
    int wave = t >> 6, lane = t & 63;
    int d0 = lane * 8;                        // 64 lanes x 8 d = 512 d's
    float s8[8] = {};
    // wave w covers l = w, w+4, ... (vector loads, independent -> MLP)
    for (int l = wave; l < L_; l += 4){
      size_t ix = ((size_t)(b*L_ + l))*D_ + d0;
      U4 xb;
      if (bf){
        xb.u = *(const uint4*)((const unsigned short*)x + ix);  // raw bits: bit-identical copy
        float2 a = bfp(xb.u.x), bq = bfp(xb.u.y), c = bfp(xb.u.z), dq = bfp(xb.u.w);
        s8[0] += a.x;  s8[1] += a.y;  s8[2] += bq.x; s8[3] += bq.y;
        s8[4] += c.x;  s8[5] += c.y;  s8[6] += dq.x; s8[7] += dq.y;
      } else {
        const float* q = (const float*)x + ix;
        float4 f0 = *(const float4*)q, f1 = *(const float4*)(q+4);
        float av[8] = {f0.x,f0.y,f0.z,f0.w, f1.x,f1.y,f1.z,f1.w};
        #pragma unroll
        for (int j = 0; j < 8; j++){ xb.us[j] = f2bfu(av[j]); s8[j] += av[j]; }
      }
      *(uint4*)(xbf + ix) = xb.u;
    }
    #pragma unroll
    for (int j = 0; j < 8; j++) pool[wave][d0+j] = s8[j];
    __syncthreads();
    float p[4] = {0.f, 0.f, 0.f, 0.f};
    #pragma unroll
    for (int rep = 0; rep < 2; rep++){
      int d = t + rep*256;
      float s = pool[0][d] + pool[1][d] + pool[2][d] + pool[3][d];
      float xfd = s * (1.f/49.f);
      #pragma unroll
      for (int e = 0; e < 4; e++) p[e] = fmaf(xfd, ldf(wg, (size_t)d*E_ + e, bf), p[e]);
    }
    #pragma unroll
    for (int off = 32; off > 0; off >>= 1){
      #pragma unroll
      for (int e = 0; e < 4; e++) p[e] += __shfl_down(p[e], off, 64);
    }
    if (lane == 0){
      #pragma unroll
      for (int e = 0; e < 4; e++) red[wave][e] = p[e];
    }
    __syncthreads();
    if (t < 4)
      logits[b*4 + t] = red[0][t]+red[1][t]+red[2][t]+red[3][t] + ldf(bg, t, bf);
  }
}

// ---------- 2. k_gate2: softmax/top-k/aux from precomputed logits (1 block) ----------
__global__ __launch_bounds__(128) void k_gate2(const void* __restrict__ x,
                                               const float* __restrict__ logits,
                                               int* __restrict__ topi, float* __restrict__ topv,
                                               void* __restrict__ out){
  __shared__ float raw[B_*E_];
  __shared__ int   sel[B_];
  __shared__ float den[E_], auxp[E_];
  int bf = detect_bf(x);
  int t = threadIdx.x;
  if (t < B_){
    float l0=logits[t*4+0], l1=logits[t*4+1], l2=logits[t*4+2], l3=logits[t*4+3];
    float m = fmaxf(fmaxf(l0,l1), fmaxf(l2,l3));
    float e0=expf(l0-m), e1=expf(l1-m), e2=expf(l2-m), e3=expf(l3-m);
    float s = e0+e1+e2+e3;
    float r[4] = {e0/s, e1/s, e2/s, e3/s};
    int i1 = 0; float v1 = r[0];
    for (int e = 1; e < 4; e++) if (r[e] > v1){ v1 = r[e]; i1 = e; }
    int i2 = -1; float v2 = -1.f;
    for (int e = 0; e < 4; e++){ if (e == i1) continue; if (r[e] > v2){ v2 = r[e]; i2 = e; } }
    if (i1 < 0 || i1 > 3) i1 = 0;
    if (i2 < 0 || i2 > 3) i2 = (i1 + 1) & 3;
    sel[t] = (1<<i1) | (1<<i2);
    for (int e = 0; e < 4; e++) raw[t*4+e] = r[e];
  }
  __syncthreads();
  if (t < E_){
    float dn = 0.f, imp = 0.f, ld = 0.f;
    for (int b = 0; b < B_; b++){
      float r = raw[b*4+t];
      int bit = (sel[b] >> t) & 1;
      if (bit) dn += r;
      imp += r; ld += (float)bit;
    }
    den[t] = dn + 1e-6f;
    imp *= (1.f/B_); ld *= (1.f/B_);
    float df = ld - imp; auxp[t] = df*df;
  }
  __syncthreads();
  if (t == 0){
    float a = 0.01f * 0.25f * (auxp[0]+auxp[1]+auxp[2]+auxp[3]);
    if (bf) ((unsigned short*)out)[16384] = f2bfu(a);
    else    ((float*)out)[16384] = a;
  }
  if (t < B_){
    float gs[4];
    for (int e = 0; e < 4; e++){
      int bit = (sel[t] >> e) & 1;
      gs[e] = bit ? raw[t*4+e] * 40.f / den[e] : 0.f;   // capacity = int(1.25*32) = 40
    }
    int i1 = 0; float v1 = gs[0];
    for (int e = 1; e < 4; e++) if (gs[e] > v1){ v1 = gs[e]; i1 = e; }
    int i2 = -1; float v2 = -1e30f;
    for (int e = 0; e < 4; e++){ if (e == i1) continue; if (gs[e] > v2){ v2 = gs[e]; i2 = e; } }
    if (i1 < 0 || i1 > 3) i1 = 0;
    if (i2 < 0 || i2 > 3) i2 = (i1 + 1) & 3;
    topi[t*2+0] = i1; topv[t*2+0] = v1;
    topi[t*2+1] = i2; topv[t*2+1] = v2;
  }
}

// ---------- 3. in_proj v3: fine-grain 16-col tiles, 8 blocks/CU ----------
// R9 diagnosis: latency-bound AND grid-limited (1024 blocks = 16 waves/CU demand,
// Occ 37%). ILP can't cover ~300cy L2 latency within VGPR budget, so raise TLP:
// each wave = one 16x16 s-tile (1 MFMA + 2 loads per K-iter), grid (64,64) ->
// 64 waves/CU demand (caps at 32 resident = 8/SIMD). Same math per output elem.
__global__ __launch_bounds__(256, 8) void k_inproj_mfma(const void* __restrict__ x,
                                                     const unsigned short* __restrict__ xbf,
                                                     const unsigned short* __restrict__ wt,
                                                     const void* __restrict__ bias,
                                                     const void* __restrict__ cw,
                                                     const void* __restrict__ cb,
                                                     const int* __restrict__ topi,
                                                     unsigned short* __restrict__ zbuf,
                                                     float* __restrict__ xc,
                                                     unsigned short* __restrict__ xchi,
                                                     unsigned short* __restrict__ xclo){
  __shared__ float xzt[49*17];                // [row][c-local 0..15], stride 17 (3.3KB)
  int bf = detect_bf(x);
  int job = blockIdx.x, nt = blockIdx.y;      // nt: 16-col tile 0..63
  int b = job >> 1;
  int e = topi[job];
  int t = threadIdx.x;
  int wave = t >> 6, lane = t & 63;
  int l16 = lane & 15, quad = lane >> 4;
  int arow = wave*16 + l16; if (arow > 48) arow = 48;   // pad rows duplicate row 48
  size_t abase = ((size_t)(b*L_ + arow))*D_;
  int ct = nt*16;
  size_t bbase = ((size_t)(e*1024 + ct + l16))*D_;
  f32x4v acc = {};
  #pragma unroll
  for (int k0 = 0; k0 < 512; k0 += 32){
    int k = k0 + quad*8;
    U4 a;  a.u  = *(const uint4*)(xbf + abase + k);     // pre-converted bf16 A
    U4 bb; bb.u = *(const uint4*)(wt + bbase + k);
    acc = __builtin_amdgcn_mfma_f32_16x16x32_bf16(a.s, bb.s, acc, 0, 0, 0);
  }
  int rb = wave*16 + quad*4;
  float bv = ldf(bias, (size_t)e*1024 + ct + l16, bf);
  if (nt >= 32){
    // z half: bias + store bf16
    #pragma unroll
    for (int r = 0; r < 4; r++){
      int row = rb + r;
      if (row < L_)
        zbuf[(size_t)job*25088 + row*D_ + (ct - 512 + l16)] = f2bfu(acc[r] + bv);
    }
    return;
  }
  // xz half: stage 16 channels to LDS, then depthwise conv
  #pragma unroll
  for (int r = 0; r < 4; r++){
    int row = rb + r;
    if (row < L_) xzt[row*17 + l16] = acc[r] + bv;
  }
  __syncthreads();
  int c = t & 15, pg = t >> 4;                // 16 channels x 16 p-groups
  int dch = ct + c;
  float wv[9];
  #pragma unroll
  for (int j = 0; j < 9; j++) wv[j] = ldf(cw, ((size_t)(e*D_ + dch))*9 + j, bf);
  float cbv = ldf(cb, (size_t)e*D_ + dch, bf);
  for (int p = pg; p < L_; p += 16){
    int h = p / 7, w = p % 7;
    float a2 = cbv;
    #pragma unroll
    for (int dy = 0; dy < 3; dy++){
      int hh = h + dy - 1; if (hh < 0 || hh >= 7) continue;
      #pragma unroll
      for (int dx = 0; dx < 3; dx++){
        int ww = w + dx - 1; if (ww < 0 || ww >= 7) continue;
        a2 = fmaf(xzt[(hh*7+ww)*17 + c], wv[dy*3+dx], a2);
      }
    }
    float sv = a2 * (1.f/(1.f+expf(-a2)));
    size_t oix = (size_t)job*25088 + (size_t)p*D_ + dch;
    xc[oix] = sv;
    unsigned int ui = __float_as_uint(sv);
    unsigned short hh2 = (unsigned short)(ui >> 16);    // trunc
    xchi[oix] = hh2;
    xclo[oix] = f2bfu(sv - bf2f(hh2));
  }
}

// ---------- 5. x_proj v5: 512-thr blocks, K split across wave pairs + LDS reduce ----------
// Same grid-occupancy diagnosis: 8 waves/block (4 col-tiles x 2 K-halves) doubles
// wave demand to 32/CU. Halves combined with one f32 add (reassociation ~1ulp).
__global__ __launch_bounds__(512, 8) void k_xproj(const void* __restrict__ x,
                                               const void* __restrict__ xpw,
                                               const int* __restrict__ topi,
                                               const unsigned short* __restrict__ xchi,
                                               const unsigned short* __restrict__ xclo,
                                               float* __restrict__ xdbl){
  __shared__ float rsum[4*64*4];              // 4KB: upper-half partial accs
  int bf = detect_bf(x);
  int kq = blockIdx.x, job = blockIdx.y;
  int k = kq & 3, q = kq >> 2;
  int t = threadIdx.x;
  int wave = t >> 6, lane = t & 63;
  int wcol = wave & 3, khalf = wave >> 2;
  int l16 = lane & 15, quad = lane >> 4;
  int e = topi[job];
  int arow = q*16 + l16; if (arow > 48) arow = 48;      // q=3 pad rows dup row 48
  int m = dirmap(k, arow);
  const unsigned short* ahp = xchi + (size_t)job*25088 + (size_t)m*D_;
  const unsigned short* alp = xclo + (size_t)job*25088 + (size_t)m*D_;
  size_t bbase = (((size_t)(e*KD_+k))*64 + wcol*16 + l16)*D_;
  int kbase = khalf*256;
  f32x4v acc = {};
  #pragma unroll
  for (int k0 = 0; k0 < 256; k0 += 32){
    int kk = kbase + k0 + quad*8;
    U4 Ahi, Alo;
    Ahi.u = *(const uint4*)(ahp + kk);
    Alo.u = *(const uint4*)(alp + kk);
    U4 bb = ldbf8(xpw, bbase + kk, bf);
    acc = __builtin_amdgcn_mfma_f32_16x16x32_bf16(Ahi.s, bb.s, acc, 0, 0, 0);
    acc = __builtin_amdgcn_mfma_f32_16x16x32_bf16(Alo.s, bb.s, acc, 0, 0, 0);
  }
  if (khalf == 1){
    #pragma unroll
    for (int r = 0; r < 4; r++) rsum[(wcol*64 + lane)*4 + r] = acc[r];
  }
  __syncthreads();
  if (khalf == 0){
    float* outb = xdbl + ((size_t)(job*KD_+k))*3136;
    int rb = q*16 + quad*4;
    int c = wcol*16 + l16;
    #pragma unroll
    for (int r = 0; r < 4; r++){
      int row = rb + r;
      if (row < L_) outb[row*64 + c] = acc[r] + rsum[(wcol*64 + lane)*4 + r];
    }
  }
}

// ---------- 6. k_scan v9b: v8 structure, instruction-trimmed hot loop (builtin-safe) ----------
// CONFIRMED R6: k_scan is CU-issue-bound; instruction trim took it 55 -> <43us.
__global__ __launch_bounds__(256, 2) void k_scan(const void* __restrict__ x,
                                              const void* __restrict__ dtw,
                                              const void* __restrict__ dtb_,
                                              const void* __restrict__ alog,
                                              const void* __restrict__ ds_,
                                              const int* __restrict__ topi,
                                              const float* __restrict__ xc,
                                              const float* __restrict__ xdbl,
                                              unsigned short* __restrict__ ybuf){
  int bf = detect_bf(x);
  int kz = blockIdx.x, job = blockIdx.y;
  int k = kz & 3, dz2 = kz >> 2;              // dz2 = d-half (256 d's per block)
  int t = threadIdx.x;
  int e = topi[job];
  int ek = e*KD_ + k;
  __shared__ float bc[49*32];                 // [l][B(16)|C(16)]
  __shared__ float dtl[49*260];               // dt[l][d_local 0..255], stride 260
  const float* xdb = xdbl + ((size_t)(job*KD_+k))*3136;
  // stage B/C columns (xdbl cols 32..63) -> bc
  {
    const float4* src4 = (const float4*)xdb;
    for (int i = t; i < 392; i += 256){
      int row = i >> 3, c = i & 7;
      ((float4*)bc)[row*8 + c] = src4[row*16 + 8 + c];
    }
  }
  int w = t >> 6, lane = t & 63;
  // ---- phase 1: dt GEMM; wave w computes its own 64-d slice (cols w*64..w*64+63) ----
  {
    int l16 = lane & 15, quad4 = lane >> 4;
    // B frags hoisted (reused across 4 row-tiles)
    U4 Bv[4];
    #pragma unroll
    for (int nt = 0; nt < 4; nt++){
      int d = dz2*256 + w*64 + nt*16 + l16;
      Bv[nt] = ldbf8(dtw, ((size_t)ek*D_ + d)*RK_ + quad4*8, bf);
    }
    f32x4v acc[4][4] = {};
    #pragma unroll
    for (int rt = 0; rt < 4; rt++){
      int arow = rt*16 + l16; if (arow > 48) arow = 48;
      const float* ap = xdb + arow*64 + quad4*8;        // dt_raw cols 0..31
      float4 f0 = *(const float4*)ap, f1 = *(const float4*)(ap+4);
      float av[8] = {f0.x,f0.y,f0.z,f0.w, f1.x,f1.y,f1.z,f1.w};
      U4 Ahi, Alo;
      split8(av, Ahi, Alo);
      #pragma unroll
      for (int nt = 0; nt < 4; nt++){
        acc[rt][nt] = __builtin_amdgcn_mfma_f32_16x16x32_bf16(Ahi.s, Bv[nt].s, acc[rt][nt], 0, 0, 0);
        acc[rt][nt] = __builtin_amdgcn_mfma_f32_16x16x32_bf16(Alo.s, Bv[nt].s, acc[rt][nt], 0, 0, 0);
      }
    }
    #pragma unroll
    for (int nt = 0; nt < 4; nt++){
      int d = dz2*256 + w*64 + nt*16 + l16;
      float bias = ldf(dtb_, (size_t)ek*D_ + d, bf);
      int dloc = w*64 + nt*16 + l16;
      #pragma unroll
      for (int rt = 0; rt < 4; rt++){
        #pragma unroll
        for (int r = 0; r < 4; r++){
          int l = rt*16 + quad4*4 + r;
          if (l < L_){
            float v = acc[rt][nt][r] + bias;
            dtl[l*260 + dloc] = fmaxf(v, 0.f) + __logf(1.f + __expf(-fabsf(v)));
          }
        }
      }
    }
  }
  // ---- phase 2 params: thread owns 4 consecutive d's (quad q) x 4 states (ng) ----
  int q4 = (lane >> 2) * 4;                   // 0,4,..,60 within wave's 64-d slice
  int ng = lane & 3;                          // state quad: states ng*4..ng*4+3
  int dgl = dz2*256 + w*64 + q4;              // global d of first owned d
  float A2[4][4], Dsv[4];
  #pragma unroll
  for (int jj = 0; jj < 4; jj++){
    int dj = dgl + jj;
    f4s ar = ldf4(alog, ((size_t)ek*D_ + dj)*NS_ + ng*4, bf);
    #pragma unroll
    for (int n = 0; n < 4; n++) A2[jj][n] = -expf(ar.v[n]) * 1.44269504f;
    Dsv[jj] = ldf(ds_, (size_t)ek*D_ + dj, bf);
  }
  __syncthreads();
  // ---- phase 2: scan, 7 chunks of 7 with x_t batch prefetch (L2-hot xc) ----
  float h[4][4];
  #pragma unroll
  for (int jj = 0; jj < 4; jj++)
    #pragma unroll
    for (int n = 0; n < 4; n++) h[jj][n] = 0.f;
  const float* xcb = xc + (size_t)job*25088;
  unsigned short* yb = ybuf + ((size_t)(job*KD_ + k))*25088;
  int dtbase = w*64 + q4;
  for (int c0 = 0; c0 < 49; c0 += 7){
    float4 xv[7];
    #pragma unroll
    for (int j = 0; j < 7; j++){
      int m = dirmap(k, c0 + j);
      xv[j] = *(const float4*)(xcb + (size_t)m*D_ + dgl);
    }
    #pragma unroll
    for (int j = 0; j < 7; j++){
      int l = c0 + j;
      float4 dt4 = *(const float4*)&dtl[l*260 + dtbase];
      float4 B4 = *(const float4*)&bc[l*32 + ng*4];
      float4 C4 = *(const float4*)&bc[l*32 + 16 + ng*4];
      float Ba[4] = {B4.x, B4.y, B4.z, B4.w};
      float Ca[4] = {C4.x, C4.y, C4.z, C4.w};
      float dta[4] = {dt4.x, dt4.y, dt4.z, dt4.w};
      float xa[4]  = {xv[j].x, xv[j].y, xv[j].z, xv[j].w};
      float ys[4];
      #pragma unroll
      for (int jj = 0; jj < 4; jj++){
        float dt = dta[jj], x_t = xa[jj];
        float dtx = dt * x_t;
        float y = 0.f;
        #pragma unroll
        for (int n = 0; n < 4; n++){
          float en = fast_exp2(dt * A2[jj][n]);
          h[jj][n] = fmaf(h[jj][n], en, dtx * Ba[n]);
          y = fmaf(h[jj][n], Ca[n], y);
        }
        y = quad_add4(y);                     // sum over 4 state-quads (VALU DPP)
        ys[jj] = fmaf(Dsv[jj], x_t, y);
      }
      if (ng == 0){
        uint2 o;
        o.x = cvtpk_bf16(ys[0], ys[1]);
        o.y = cvtpk_bf16(ys[2], ys[3]);
        *(uint2*)(yb + (size_t)l*D_ + dgl) = o;
      }
    }
  }
}

// ---------- 7a. k_final_a: per-(job, p mod 4) partial pools (256 blocks) ----------
__global__ __launch_bounds__(512) void k_final_a(const void* __restrict__ x,
                                                 const void* __restrict__ og,
                                                 const void* __restrict__ ob,
                                                 const int* __restrict__ topi,
                                                 const unsigned short* __restrict__ ybuf,
                                                 const unsigned short* __restrict__ zbuf,
                                                 float* __restrict__ partial){
  __shared__ float pool[8][512];
  int bf = detect_bf(x);
  int job = blockIdx.x, q = blockIdx.y, t = threadIdx.x;
  int wave = t >> 6, lane = t & 63;
  int e = topi[job];
  int d0 = lane*8;
  const unsigned short* yb = ybuf + (size_t)job*KD_*25088;
  const unsigned short* zb = zbuf + (size_t)job*25088;
  float g[8], o[8];
  {
    f8s gg = ldf8(og, (size_t)e*D_ + d0, bf);
    f8s oo = ldf8(ob, (size_t)e*D_ + d0, bf);
    #pragma unroll
    for (int j = 0; j < 8; j++){ g[j] = gg.v[j]; o[j] = oo.v[j]; }
  }
  float acc[8] = {};
  for (int i = wave; i <= 12; i += 8){
    int p = q + 4*i;
    if (p >= L_) break;
    float v[8] = {};
    #pragma unroll
    for (int k = 0; k < KD_; k++){
      int l = dirmap(k, p);                   // involution
      U4 r; r.u = *(const uint4*)(yb + (size_t)k*25088 + (size_t)l*D_ + d0);
      #pragma unroll
      for (int j = 0; j < 8; j++) v[j] += bf2f(r.us[j]);
    }
    float s = 0.f, ss = 0.f;
    #pragma unroll
    for (int j = 0; j < 8; j++){ s += v[j]; ss += v[j]*v[j]; }
    #pragma unroll
    for (int off = 32; off > 0; off >>= 1){
      s  += __shfl_xor(s,  off, 64);
      ss += __shfl_xor(ss, off, 64);
    }
    float mu = s*(1.f/512.f);
    float var = ss*(1.f/512.f) - mu*mu;
    float rs = rsqrtf(var + 1e-5f);
    U4 zz; zz.u = *(const uint4*)(zb + (size_t)p*D_ + d0);
    #pragma unroll
    for (int j = 0; j < 8; j++){
      float zv = bf2f(zz.us[j]);
      acc[j] += ((v[j]-mu)*rs*g[j] + o[j]) * silu_f(zv);
    }
  }
  #pragma unroll
  for (int j = 0; j < 8; j++) pool[wave][d0+j] = acc[j];
  __syncthreads();
  float pd = pool[0][t]+pool[1][t]+pool[2][t]+pool[3][t]
           + pool[4][t]+pool[5][t]+pool[6][t]+pool[7][t];
  partial[((size_t)(job*4 + q))*512 + t] = pd;
}

// ---------- 7b. k_finmix: combine partials + final LN for both slots -> out ----------
__global__ __launch_bounds__(512) void k_finmix(const void* __restrict__ x,
                                                const void* __restrict__ ngg,
                                                const void* __restrict__ nbb,
                                                const int* __restrict__ topi,
                                                const float* __restrict__ topv,
                                                const float* __restrict__ partial,
                                                void* __restrict__ out){
  __shared__ float red[32];
  int bf = detect_bf(x);
  int b = blockIdx.x, t = threadIdx.x;
  int wave = t >> 6, lane = t & 63;
  int j0 = 2*b, j1 = 2*b + 1;
  int e0 = topi[j0], e1 = topi[j1];
  float g0 = topv[j0], g1 = topv[j1];
  const float* p0 = partial + (size_t)j0*4*512;
  const float* p1 = partial + (size_t)j1*4*512;
  float pd0 = (p0[t] + p0[512+t] + p0[1024+t] + p0[1536+t]) * (1.f/49.f);
  float pd1 = (p1[t] + p1[512+t] + p1[1024+t] + p1[1536+t]) * (1.f/49.f);
  float s0 = pd0, ss0 = pd0*pd0, s1 = pd1, ss1 = pd1*pd1;
  #pragma unroll
  for (int off = 32; off > 0; off >>= 1){
    s0  += __shfl_down(s0,  off, 64);
    ss0 += __shfl_down(ss0, off, 64);
    s1  += __shfl_down(s1,  off, 64);
    ss1 += __shfl_down(ss1, off, 64);
  }
  if (lane == 0){
    red[wave] = s0; red[8+wave] = ss0; red[16+wave] = s1; red[24+wave] = ss1;
  }
  __syncthreads();
  s0 = red[0]+red[1]+red[2]+red[3]+red[4]+red[5]+red[6]+red[7];
  ss0 = red[8]+red[9]+red[10]+red[11]+red[12]+red[13]+red[14]+red[15];
  s1 = red[16]+red[17]+red[18]+red[19]+red[20]+red[21]+red[22]+red[23];
  ss1 = red[24]+red[25]+red[26]+red[27]+red[28]+red[29]+red[30]+red[31];
  float mu0 = s0*(1.f/512.f), var0 = ss0*(1.f/512.f) - mu0*mu0;
  float rs0 = rsqrtf(var0 + 1e-5f);
  float mu1 = s1*(1.f/512.f), var1 = ss1*(1.f/512.f) - mu1*mu1;
  float rs1 = rsqrtf(var1 + 1e-5f);
  float v0 = ((pd0-mu0)*rs0*ldf(ngg, (size_t)e0*D_+t, bf) + ldf(nbb, (size_t)e0*D_+t, bf)) * g0;
  float v1 = ((pd1-mu1)*rs1*ldf(ngg, (size_t)e1*D_+t, bf) + ldf(nbb, (size_t)e1*D_+t, bf)) * g1;
  float v = v0 + v1;
  if (bf) ((unsigned short*)out)[b*D_ + t] = f2bfu(v);
  else    ((float*)out)[b*D_ + t] = v;
}

extern "C" void kernel_launch(void* const* d_in, const int* in_sizes, int n_in,
                              void* d_out, int out_size, void* d_ws, size_t ws_size,
                              hipStream_t stream){
  const void* x    = d_in[0];
  const void* wg   = d_in[1];
  const void* bg   = d_in[2];
  const void* ipw  = d_in[3];
  const void* ipb  = d_in[4];
  const void* cw   = d_in[5];
  const void* cb   = d_in[6];
  const void* xpw  = d_in[7];
  const void* dtw  = d_in[8];
  const void* dtb  = d_in[9];
  const void* alog = d_in[10];
  const void* dss  = d_in[11];
  const void* ogg  = d_in[12];
  const void* obb  = d_in[13];
  const void* ngg  = d_in[14];
  const void* nbb  = d_in[15];
  float* wsf = (float*)d_ws;
  int*   topi  = (int*)d_ws + 16;                          // [16..80)
  float* topv  = wsf + 96;                                 // [96..160)
  float* logits= wsf + 256;                                // 128
  float* xc    = wsf + 16640;                              // 1605632 (6.4MB)
  float* xdbl  = wsf + 1622272;                            // 802816 (3.2MB)
  unsigned short* zbuf = (unsigned short*)(wsf + 2425088); // 1605632 bf16 (3.2MB)
  // ybuf region (12.8MB bf16) is written only by k_scan; until then it hosts:
  //   wtrans [0 .. 2097152)        4MB   written k_prep, read k_inproj
  //   xchi   [2097152 .. 3702784)  3.2MB written k_inproj, read k_xproj
  //   xclo   [3702784 .. 5308416)  3.2MB written k_inproj, read k_xproj
  //   xbf    [5308416 .. 6111232)  1.6MB written k_prep, read k_inproj
  unsigned short* ybuf   = (unsigned short*)(wsf + 3260672);
  unsigned short* wtrans = ybuf;
  unsigned short* xchi   = ybuf + 2097152;
  unsigned short* xclo   = ybuf + 3702784;
  unsigned short* xbf    = ybuf + 5308416;
  float* partial = wsf + 6471936;                          // 64*4*512 = 131072 (~0.5MB)

  k_prep  <<<544, 256, 0, stream>>>(x, ipw, wg, bg, wtrans, xbf, logits);
  k_gate2 <<<1, 128, 0, stream>>>(x, logits, topi, topv, d_out);
  k_inproj_mfma<<<dim3(64,64), 256, 0, stream>>>(x, xbf, wtrans, ipb, cw, cb, topi, zbuf, xc, xchi, xclo);
  k_xproj <<<dim3(16,64), 512, 0, stream>>>(x, xpw, topi, xchi, xclo, xdbl);
  k_scan  <<<dim3(8,64), 256, 0, stream>>>(x, dtw, dtb, alog, dss, topi, xc, xdbl, ybuf);
  k_final_a<<<dim3(64,4), 512, 0, stream>>>(x, ogg, obb, topi, ybuf, zbuf, partial);
  k_finmix<<<32, 512, 0, stream>>>(x, ngg, nbb, topi, topv, partial, d_out);
}

// Round 11
// 200.972 us; speedup vs baseline: 1.1689x; 1.1689x over previous
//
#include <hip/hip_runtime.h>
#include <hip/hip_bf16.h>

#define B_   32
#define D_   512
#define L_   49
#define E_   4
#define KD_  4
#define NS_  16
#define RK_  32
#define JOBS_ 64

typedef short s16x8 __attribute__((ext_vector_type(8)));
typedef float f32x4v __attribute__((ext_vector_type(4)));
union U4 { uint4 u; s16x8 s; unsigned short us[8]; };

// ---------- helpers ----------
__device__ __forceinline__ float bf2f(unsigned short u){
  union{unsigned int i; float f;} v; v.i = ((unsigned int)u)<<16; return v.f;
}
__device__ __forceinline__ float2 bfp(unsigned int u){
  union{unsigned int i; float f;} a, b; a.i = u<<16; b.i = u & 0xffff0000u;
  return make_float2(a.f, b.f);
}
__device__ __forceinline__ unsigned short f2bfu(float f){
  union{float f; unsigned int i;} u; u.f = f;
  unsigned int r = u.i + 0x7fffu + ((u.i >> 16) & 1u);
  return (unsigned short)(r >> 16);
}
__device__ __forceinline__ float silu_f(float x){ return x / (1.f + expf(-x)); }

__device__ __forceinline__ float fast_exp2(float x){
  return __builtin_amdgcn_exp2f(x);
}
__device__ __forceinline__ float quad_add4(float y){
  float t1 = __uint_as_float(__builtin_amdgcn_mov_dpp(__float_as_uint(y), 0xB1, 0xF, 0xF, true));
  y += t1;
  float t2 = __uint_as_float(__builtin_amdgcn_mov_dpp(__float_as_uint(y), 0x4E, 0xF, 0xF, true));
  y += t2;
  return y;
}
__device__ __forceinline__ unsigned cvtpk_bf16(float lo, float hi){
  unsigned r; asm("v_cvt_pk_bf16_f32 %0, %1, %2" : "=v"(r) : "v"(lo), "v"(hi)); return r;
}

// inline dtype detection: wave-ballot over x[0..63] viewed as bf16 (~5 instr).
__device__ __forceinline__ int detect_bf(const void* x){
  unsigned short u = ((const unsigned short*)x)[threadIdx.x & 63];
  int e = (u >> 7) & 0xff;
  unsigned long long m = __ballot(e >= 96 && e < 160);
  return __popcll(m) >= 56;
}

// dtype-agnostic loads: bf=1 -> bf16 (ushort), bf=0 -> float32
__device__ __forceinline__ float ldf(const void* p, size_t i, int bf){
  return bf ? bf2f(((const unsigned short*)p)[i]) : ((const float*)p)[i];
}
struct f8s{ float v[8]; };
__device__ __forceinline__ f8s ldf8(const void* p, size_t i, int bf){
  f8s r;
  if (bf){
    uint4 u = *(const uint4*)((const unsigned short*)p + i);
    float2 x = bfp(u.x), y = bfp(u.y), z = bfp(u.z), w = bfp(u.w);
    r.v[0]=x.x; r.v[1]=x.y; r.v[2]=y.x; r.v[3]=y.y;
    r.v[4]=z.x; r.v[5]=z.y; r.v[6]=w.x; r.v[7]=w.y;
  } else {
    const float4* q = (const float4*)((const float*)p + i);
    float4 a = q[0], b = q[1];
    r.v[0]=a.x; r.v[1]=a.y; r.v[2]=a.z; r.v[3]=a.w;
    r.v[4]=b.x; r.v[5]=b.y; r.v[6]=b.z; r.v[7]=b.w;
  }
  return r;
}
struct f4s{ float v[4]; };
__device__ __forceinline__ f4s ldf4(const void* p, size_t i, int bf){
  f4s r;
  if (bf){
    uint2 u = *(const uint2*)((const unsigned short*)p + i);
    float2 a = bfp(u.x), b = bfp(u.y);
    r.v[0]=a.x; r.v[1]=a.y; r.v[2]=b.x; r.v[3]=b.y;
  } else {
    float4 a = *(const float4*)((const float*)p + i);
    r.v[0]=a.x; r.v[1]=a.y; r.v[2]=a.z; r.v[3]=a.w;
  }
  return r;
}
// load 8 elems as bf16 frag (bf16: direct; fp32: convert)
__device__ __forceinline__ U4 ldbf8(const void* p, size_t i, int bf){
  U4 r;
  if (bf){
    r.u = *(const uint4*)((const unsigned short*)p + i);
  } else {
    const float* q = (const float*)p + i;
    float4 a = *(const float4*)q, b = *(const float4*)(q+4);
    r.u.x = (unsigned)f2bfu(a.x) | ((unsigned)f2bfu(a.y) << 16);
    r.u.y = (unsigned)f2bfu(a.z) | ((unsigned)f2bfu(a.w) << 16);
    r.u.z = (unsigned)f2bfu(b.x) | ((unsigned)f2bfu(b.y) << 16);
    r.u.w = (unsigned)f2bfu(b.z) | ((unsigned)f2bfu(b.w) << 16);
  }
  return r;
}
// split 8 fp32 into hi (truncated bf16) + lo (rounded residual bf16)
__device__ __forceinline__ void split8(const float av[8], U4& hi, U4& lo){
  #pragma unroll
  for (int j = 0; j < 8; j++){
    union{float f; unsigned int i;} u; u.f = av[j];
    unsigned short h = (unsigned short)(u.i >> 16);   // trunc — residual goes to lo
    hi.us[j] = h;
    lo.us[j] = f2bfu(av[j] - bf2f(h));
  }
}

// direction index map: xs[k,d,l] = xc[d, dirmap(k,l)]; all four maps are involutions.
__device__ __forceinline__ int dirmap(int k, int l){
  if (k == 0) return l;
  if (k == 1) return 48 - l;
  if (k == 2) return (l % 7) * 7 + l / 7;
  int l2 = 48 - l; return (l2 % 7) * 7 + l2 / 7;
}

// ---------- 1. k_prep: wtrans (blocks 0..511) + bgate logits + xbf (blocks 512..543) ----------
__global__ __launch_bounds__(256) void k_prep(const void* __restrict__ x,
                                              const void* __restrict__ w,
                                              const void* __restrict__ wg,
                                              const void* __restrict__ bg,
                                              unsigned short* __restrict__ wt,
                                              unsigned short* __restrict__ xbf,
                                              float* __restrict__ logits){
  __shared__ unsigned short tile[64][72];
  __shared__ float red[4][4];
  __shared__ float pool[4][512];
  int bf = detect_bf(x);
  int blk = blockIdx.x;
  int t = threadIdx.x;
  if (blk < 512){
    int e = blk >> 7, cb = (blk >> 3) & 15, db = blk & 7;
    #pragma unroll
    for (int r = 0; r < 4; r++){
      int d  = r*16 + (t>>4);
      int c0 = (t&15)*4;
      size_t g = ((size_t)e*512 + db*64 + d)*1024 + cb*64 + c0;
      if (bf){
        uint2 u = *(const uint2*)((const unsigned short*)w + g);
        tile[c0+0][d] = (unsigned short)(u.x & 0xffffu);
        tile[c0+1][d] = (unsigned short)(u.x >> 16);
        tile[c0+2][d] = (unsigned short)(u.y & 0xffffu);
        tile[c0+3][d] = (unsigned short)(u.y >> 16);
      } else {
        float4 v = *(const float4*)((const float*)w + g);
        tile[c0+0][d] = f2bfu(v.x);
        tile[c0+1][d] = f2bfu(v.y);
        tile[c0+2][d] = f2bfu(v.z);
        tile[c0+3][d] = f2bfu(v.w);
      }
    }
    __syncthreads();
    #pragma unroll
    for (int r = 0; r < 2; r++){
      int o = r*256 + t;
      int c = o >> 3, d0 = (o & 7)*8;
      uint4 v = *(const uint4*)&tile[c][d0];
      *(uint4*)(wt + ((size_t)e*1024 + cb*64 + c)*512 + db*64 + d0) = v;
    }
  } else {
    int b = blk - 512;
    int wave = t >> 6, lane = t & 63;
    int d0 = lane * 8;                        // 64 lanes x 8 d = 512 d's
    float s8[8] = {};
    for (int l = wave; l < L_; l += 4){
      size_t ix = ((size_t)(b*L_ + l))*D_ + d0;
      U4 xb;
      if (bf){
        xb.u = *(const uint4*)((const unsigned short*)x + ix);  // raw bits: bit-identical copy
        float2 a = bfp(xb.u.x), bq = bfp(xb.u.y), c = bfp(xb.u.z), dq = bfp(xb.u.w);
        s8[0] += a.x;  s8[1] += a.y;  s8[2] += bq.x; s8[3] += bq.y;
        s8[4] += c.x;  s8[5] += c.y;  s8[6] += dq.x; s8[7] += dq.y;
      } else {
        const float* q = (const float*)x + ix;
        float4 f0 = *(const float4*)q, f1 = *(const float4*)(q+4);
        float av[8] = {f0.x,f0.y,f0.z,f0.w, f1.x,f1.y,f1.z,f1.w};
        #pragma unroll
        for (int j = 0; j < 8; j++){ xb.us[j] = f2bfu(av[j]); s8[j] += av[j]; }
      }
      *(uint4*)(xbf + ix) = xb.u;
    }
    #pragma unroll
    for (int j = 0; j < 8; j++) pool[wave][d0+j] = s8[j];
    __syncthreads();
    float p[4] = {0.f, 0.f, 0.f, 0.f};
    #pragma unroll
    for (int rep = 0; rep < 2; rep++){
      int d = t + rep*256;
      float s = pool[0][d] + pool[1][d] + pool[2][d] + pool[3][d];
      float xfd = s * (1.f/49.f);
      #pragma unroll
      for (int e = 0; e < 4; e++) p[e] = fmaf(xfd, ldf(wg, (size_t)d*E_ + e, bf), p[e]);
    }
    #pragma unroll
    for (int off = 32; off > 0; off >>= 1){
      #pragma unroll
      for (int e = 0; e < 4; e++) p[e] += __shfl_down(p[e], off, 64);
    }
    if (lane == 0){
      #pragma unroll
      for (int e = 0; e < 4; e++) red[wave][e] = p[e];
    }
    __syncthreads();
    if (t < 4)
      logits[b*4 + t] = red[0][t]+red[1][t]+red[2][t]+red[3][t] + ldf(bg, t, bf);
  }
}

// ---------- 2. k_gate2: softmax/top-k/aux from precomputed logits (1 block) ----------
__global__ __launch_bounds__(128) void k_gate2(const void* __restrict__ x,
                                               const float* __restrict__ logits,
                                               int* __restrict__ topi, float* __restrict__ topv,
                                               void* __restrict__ out){
  __shared__ float raw[B_*E_];
  __shared__ int   sel[B_];
  __shared__ float den[E_], auxp[E_];
  int bf = detect_bf(x);
  int t = threadIdx.x;
  if (t < B_){
    float l0=logits[t*4+0], l1=logits[t*4+1], l2=logits[t*4+2], l3=logits[t*4+3];
    float m = fmaxf(fmaxf(l0,l1), fmaxf(l2,l3));
    float e0=expf(l0-m), e1=expf(l1-m), e2=expf(l2-m), e3=expf(l3-m);
    float s = e0+e1+e2+e3;
    float r[4] = {e0/s, e1/s, e2/s, e3/s};
    int i1 = 0; float v1 = r[0];
    for (int e = 1; e < 4; e++) if (r[e] > v1){ v1 = r[e]; i1 = e; }
    int i2 = -1; float v2 = -1.f;
    for (int e = 0; e < 4; e++){ if (e == i1) continue; if (r[e] > v2){ v2 = r[e]; i2 = e; } }
    if (i1 < 0 || i1 > 3) i1 = 0;
    if (i2 < 0 || i2 > 3) i2 = (i1 + 1) & 3;
    sel[t] = (1<<i1) | (1<<i2);
    for (int e = 0; e < 4; e++) raw[t*4+e] = r[e];
  }
  __syncthreads();
  if (t < E_){
    float dn = 0.f, imp = 0.f, ld = 0.f;
    for (int b = 0; b < B_; b++){
      float r = raw[b*4+t];
      int bit = (sel[b] >> t) & 1;
      if (bit) dn += r;
      imp += r; ld += (float)bit;
    }
    den[t] = dn + 1e-6f;
    imp *= (1.f/B_); ld *= (1.f/B_);
    float df = ld - imp; auxp[t] = df*df;
  }
  __syncthreads();
  if (t == 0){
    float a = 0.01f * 0.25f * (auxp[0]+auxp[1]+auxp[2]+auxp[3]);
    if (bf) ((unsigned short*)out)[16384] = f2bfu(a);
    else    ((float*)out)[16384] = a;
  }
  if (t < B_){
    float gs[4];
    for (int e = 0; e < 4; e++){
      int bit = (sel[t] >> e) & 1;
      gs[e] = bit ? raw[t*4+e] * 40.f / den[e] : 0.f;   // capacity = int(1.25*32) = 40
    }
    int i1 = 0; float v1 = gs[0];
    for (int e = 1; e < 4; e++) if (gs[e] > v1){ v1 = gs[e]; i1 = e; }
    int i2 = -1; float v2 = -1e30f;
    for (int e = 0; e < 4; e++){ if (e == i1) continue; if (gs[e] > v2){ v2 = gs[e]; i2 = e; } }
    if (i1 < 0 || i1 > 3) i1 = 0;
    if (i2 < 0 || i2 > 3) i2 = (i1 + 1) & 3;
    topi[t*2+0] = i1; topv[t*2+0] = v1;
    topi[t*2+1] = i2; topv[t*2+1] = v2;
  }
}

// ---------- 3. in_proj v4: double-buffered LDS staging of B (canonical GEMM) ----------
// R10 post-mortem: occupancy 73% did NOT help (59us) -> per-load latency huge
// (L2 thrash, ~1000cy) and loads sat on the compute chain in every prior version.
// v4 decouples: per K-step(64), 256 threads cooperatively issue 512 independent
// 16B B-loads (latency amortized across MLP), XOR-swizzled ds_write/read (T2);
// A register-prefetched one step ahead. MFMA order unchanged -> bit-identical.
__global__ __launch_bounds__(256, 4) void k_inproj_mfma(const void* __restrict__ x,
                                                     const unsigned short* __restrict__ xbf,
                                                     const unsigned short* __restrict__ wt,
                                                     const void* __restrict__ bias,
                                                     const void* __restrict__ cw,
                                                     const void* __restrict__ cb,
                                                     const int* __restrict__ topi,
                                                     unsigned short* __restrict__ zbuf,
                                                     float* __restrict__ xc,
                                                     unsigned short* __restrict__ xchi,
                                                     unsigned short* __restrict__ xclo){
  __shared__ unsigned short smem[2*4096];     // 2 bufs x [64 col][64 k] bf16 = 16KB
  float* xzt = (float*)smem;                  // [49][68] f32 alias for conv (13.3KB)
  int bf = detect_bf(x);
  int job = blockIdx.x, nt = blockIdx.y;
  int b = job >> 1;
  int e = topi[job];
  int t = threadIdx.x;
  int wave = t >> 6, lane = t & 63;
  int l16 = lane & 15, quad = lane >> 4;
  int arow = wave*16 + l16; if (arow > 48) arow = 48;   // pad rows duplicate row 48
  size_t abase = ((size_t)(b*L_ + arow))*D_;
  int ct = nt*64;
  const unsigned short* wsrc = wt + (size_t)(e*1024 + ct)*512;
  // staging chunk ids for this thread: c and c+256 (512 x 16B chunks per step)
  f32x4v acc[4] = {};
  // prologue: stage step 0 into buf0; prefetch A frags for step 0
  #pragma unroll
  for (int cc = 0; cc < 2; cc++){
    int c = t + cc*256;
    int col = c >> 3, ko8 = c & 7;
    uint4 v = *(const uint4*)(wsrc + (size_t)col*512 + ko8*8);
    *(uint4*)(smem + col*64 + ((ko8 ^ (col & 7))*8)) = v;
  }
  U4 aA, aB;
  aA.u = *(const uint4*)(xbf + abase + quad*8);
  aB.u = *(const uint4*)(xbf + abase + 32 + quad*8);
  __syncthreads();
  for (int s = 0; s < 8; s++){
    unsigned short* cur = smem + (s & 1)*4096;
    U4 nA, nB;
    if (s < 7){
      unsigned short* nxt = smem + ((s+1) & 1)*4096;
      int k0n = (s+1)*64;
      #pragma unroll
      for (int cc = 0; cc < 2; cc++){
        int c = t + cc*256;
        int col = c >> 3, ko8 = c & 7;
        uint4 v = *(const uint4*)(wsrc + (size_t)col*512 + k0n + ko8*8);
        *(uint4*)(nxt + col*64 + ((ko8 ^ (col & 7))*8)) = v;
      }
      nA.u = *(const uint4*)(xbf + abase + k0n + quad*8);
      nB.u = *(const uint4*)(xbf + abase + k0n + 32 + quad*8);
    }
    // compute step s from cur (ks=0 -> aA, ks=1 -> aB); MFMA order == v2
    {
      int ko8 = quad;                         // ks=0
      #pragma unroll
      for (int ss = 0; ss < 4; ss++){
        int col = ss*16 + l16;
        U4 bb; bb.u = *(const uint4*)(cur + col*64 + ((ko8 ^ (col & 7))*8));
        acc[ss] = __builtin_amdgcn_mfma_f32_16x16x32_bf16(aA.s, bb.s, acc[ss], 0, 0, 0);
      }
      ko8 = 4 + quad;                         // ks=1
      #pragma unroll
      for (int ss = 0; ss < 4; ss++){
        int col = ss*16 + l16;
        U4 bb; bb.u = *(const uint4*)(cur + col*64 + ((ko8 ^ (col & 7))*8));
        acc[ss] = __builtin_amdgcn_mfma_f32_16x16x32_bf16(aB.s, bb.s, acc[ss], 0, 0, 0);
      }
    }
    aA = nA; aB = nB;
    __syncthreads();
  }
  int rb = wave*16 + quad*4;
  if (nt >= 8){
    #pragma unroll
    for (int s = 0; s < 4; s++){
      int c = ct + s*16 + l16;
      float bv = ldf(bias, (size_t)e*1024 + c, bf);
      #pragma unroll
      for (int r = 0; r < 4; r++){
        int row = rb + r;
        if (row < L_)
          zbuf[(size_t)job*25088 + row*D_ + (c - 512)] = f2bfu(acc[s][r] + bv);
      }
    }
    return;
  }
  // xz half: stage to LDS (aliases staging bufs; safe after final barrier), then conv
  #pragma unroll
  for (int s = 0; s < 4; s++){
    int cl = s*16 + l16;
    float bv = ldf(bias, (size_t)e*1024 + ct + cl, bf);
    #pragma unroll
    for (int r = 0; r < 4; r++){
      int row = rb + r;
      if (row < L_) xzt[row*68 + cl] = acc[s][r] + bv;
    }
  }
  __syncthreads();
  int c = t & 63, pg = t >> 6;                // 64 channels x 4 p-groups
  int dch = ct + c;
  float wv[9];
  #pragma unroll
  for (int j = 0; j < 9; j++) wv[j] = ldf(cw, ((size_t)(e*D_ + dch))*9 + j, bf);
  float cbv = ldf(cb, (size_t)e*D_ + dch, bf);
  for (int p = pg; p < L_; p += 4){
    int h = p / 7, w = p % 7;
    float a2 = cbv;
    #pragma unroll
    for (int dy = 0; dy < 3; dy++){
      int hh = h + dy - 1; if (hh < 0 || hh >= 7) continue;
      #pragma unroll
      for (int dx = 0; dx < 3; dx++){
        int ww = w + dx - 1; if (ww < 0 || ww >= 7) continue;
        a2 = fmaf(xzt[(hh*7+ww)*68 + c], wv[dy*3+dx], a2);
      }
    }
    float sv = a2 * (1.f/(1.f+expf(-a2)));
    size_t oix = (size_t)job*25088 + (size_t)p*D_ + dch;
    xc[oix] = sv;
    unsigned int ui = __float_as_uint(sv);
    unsigned short hh2 = (unsigned short)(ui >> 16);    // trunc
    xchi[oix] = hh2;
    xclo[oix] = f2bfu(sv - bf2f(hh2));
  }
}

// ---------- 5. x_proj (R9 version): A pre-split (xchi/xclo), K-loop unrolled ----------
__global__ __launch_bounds__(256, 4) void k_xproj(const void* __restrict__ x,
                                               const void* __restrict__ xpw,
                                               const int* __restrict__ topi,
                                               const unsigned short* __restrict__ xchi,
                                               const unsigned short* __restrict__ xclo,
                                               float* __restrict__ xdbl){
  int bf = detect_bf(x);
  int kq = blockIdx.x, job = blockIdx.y;
  int k = kq & 3, q = kq >> 2;
  int t = threadIdx.x;
  int wave = t >> 6, lane = t & 63;
  int l16 = lane & 15, quad = lane >> 4;
  int e = topi[job];
  int arow = q*16 + l16; if (arow > 48) arow = 48;      // q=3 pad rows dup row 48
  int m = dirmap(k, arow);
  const unsigned short* ahp = xchi + (size_t)job*25088 + (size_t)m*D_;
  const unsigned short* alp = xclo + (size_t)job*25088 + (size_t)m*D_;
  size_t bbase = (((size_t)(e*KD_+k))*64 + wave*16 + l16)*D_;
  f32x4v acc = {};
  #pragma unroll
  for (int k0 = 0; k0 < 512; k0 += 32){
    int kk = k0 + quad*8;
    U4 Ahi, Alo;
    Ahi.u = *(const uint4*)(ahp + kk);
    Alo.u = *(const uint4*)(alp + kk);
    U4 bb = ldbf8(xpw, bbase + kk, bf);
    acc = __builtin_amdgcn_mfma_f32_16x16x32_bf16(Ahi.s, bb.s, acc, 0, 0, 0);
    acc = __builtin_amdgcn_mfma_f32_16x16x32_bf16(Alo.s, bb.s, acc, 0, 0, 0);
  }
  float* outb = xdbl + ((size_t)(job*KD_+k))*3136;
  int rb = q*16 + quad*4;
  int c = wave*16 + l16;
  #pragma unroll
  for (int r = 0; r < 4; r++){
    int row = rb + r;
    if (row < L_) outb[row*64 + c] = acc[r];
  }
}

// ---------- 6. k_scan v9b: v8 structure, instruction-trimmed hot loop (builtin-safe) ----------
// CONFIRMED R6: k_scan is CU-issue-bound; instruction trim took it 55 -> <43us.
__global__ __launch_bounds__(256, 2) void k_scan(const void* __restrict__ x,
                                              const void* __restrict__ dtw,
                                              const void* __restrict__ dtb_,
                                              const void* __restrict__ alog,
                                              const void* __restrict__ ds_,
                                              const int* __restrict__ topi,
                                              const float* __restrict__ xc,
                                              const float* __restrict__ xdbl,
                                              unsigned short* __restrict__ ybuf){
  int bf = detect_bf(x);
  int kz = blockIdx.x, job = blockIdx.y;
  int k = kz & 3, dz2 = kz >> 2;              // dz2 = d-half (256 d's per block)
  int t = threadIdx.x;
  int e = topi[job];
  int ek = e*KD_ + k;
  __shared__ float bc[49*32];                 // [l][B(16)|C(16)]
  __shared__ float dtl[49*260];               // dt[l][d_local 0..255], stride 260
  const float* xdb = xdbl + ((size_t)(job*KD_+k))*3136;
  // stage B/C columns (xdbl cols 32..63) -> bc
  {
    const float4* src4 = (const float4*)xdb;
    for (int i = t; i < 392; i += 256){
      int row = i >> 3, c = i & 7;
      ((float4*)bc)[row*8 + c] = src4[row*16 + 8 + c];
    }
  }
  int w = t >> 6, lane = t & 63;
  // ---- phase 1: dt GEMM; wave w computes its own 64-d slice (cols w*64..w*64+63) ----
  {
    int l16 = lane & 15, quad4 = lane >> 4;
    U4 Bv[4];
    #pragma unroll
    for (int nt = 0; nt < 4; nt++){
      int d = dz2*256 + w*64 + nt*16 + l16;
      Bv[nt] = ldbf8(dtw, ((size_t)ek*D_ + d)*RK_ + quad4*8, bf);
    }
    f32x4v acc[4][4] = {};
    #pragma unroll
    for (int rt = 0; rt < 4; rt++){
      int arow = rt*16 + l16; if (arow > 48) arow = 48;
      const float* ap = xdb + arow*64 + quad4*8;        // dt_raw cols 0..31
      float4 f0 = *(const float4*)ap, f1 = *(const float4*)(ap+4);
      float av[8] = {f0.x,f0.y,f0.z,f0.w, f1.x,f1.y,f1.z,f1.w};
      U4 Ahi, Alo;
      split8(av, Ahi, Alo);
      #pragma unroll
      for (int nt = 0; nt < 4; nt++){
        acc[rt][nt] = __builtin_amdgcn_mfma_f32_16x16x32_bf16(Ahi.s, Bv[nt].s, acc[rt][nt], 0, 0, 0);
        acc[rt][nt] = __builtin_amdgcn_mfma_f32_16x16x32_bf16(Alo.s, Bv[nt].s, acc[rt][nt], 0, 0, 0);
      }
    }
    #pragma unroll
    for (int nt = 0; nt < 4; nt++){
      int d = dz2*256 + w*64 + nt*16 + l16;
      float bias = ldf(dtb_, (size_t)ek*D_ + d, bf);
      int dloc = w*64 + nt*16 + l16;
      #pragma unroll
      for (int rt = 0; rt < 4; rt++){
        #pragma unroll
        for (int r = 0; r < 4; r++){
          int l = rt*16 + quad4*4 + r;
          if (l < L_){
            float v = acc[rt][nt][r] + bias;
            dtl[l*260 + dloc] = fmaxf(v, 0.f) + __logf(1.f + __expf(-fabsf(v)));
          }
        }
      }
    }
  }
  // ---- phase 2 params: thread owns 4 consecutive d's (quad q) x 4 states (ng) ----
  int q4 = (lane >> 2) * 4;                   // 0,4,..,60 within wave's 64-d slice
  int ng = lane & 3;                          // state quad: states ng*4..ng*4+3
  int dgl = dz2*256 + w*64 + q4;              // global d of first owned d
  float A2[4][4], Dsv[4];
  #pragma unroll
  for (int jj = 0; jj < 4; jj++){
    int dj = dgl + jj;
    f4s ar = ldf4(alog, ((size_t)ek*D_ + dj)*NS_ + ng*4, bf);
    #pragma unroll
    for (int n = 0; n < 4; n++) A2[jj][n] = -expf(ar.v[n]) * 1.44269504f;
    Dsv[jj] = ldf(ds_, (size_t)ek*D_ + dj, bf);
  }
  __syncthreads();
  // ---- phase 2: scan, 7 chunks of 7 with x_t batch prefetch (L2-hot xc) ----
  float h[4][4];
  #pragma unroll
  for (int jj = 0; jj < 4; jj++)
    #pragma unroll
    for (int n = 0; n < 4; n++) h[jj][n] = 0.f;
  const float* xcb = xc + (size_t)job*25088;
  unsigned short* yb = ybuf + ((size_t)(job*KD_ + k))*25088;
  int dtbase = w*64 + q4;
  for (int c0 = 0; c0 < 49; c0 += 7){
    float4 xv[7];
    #pragma unroll
    for (int j = 0; j < 7; j++){
      int m = dirmap(k, c0 + j);
      xv[j] = *(const float4*)(xcb + (size_t)m*D_ + dgl);
    }
    #pragma unroll
    for (int j = 0; j < 7; j++){
      int l = c0 + j;
      float4 dt4 = *(const float4*)&dtl[l*260 + dtbase];
      float4 B4 = *(const float4*)&bc[l*32 + ng*4];
      float4 C4 = *(const float4*)&bc[l*32 + 16 + ng*4];
      float Ba[4] = {B4.x, B4.y, B4.z, B4.w};
      float Ca[4] = {C4.x, C4.y, C4.z, C4.w};
      float dta[4] = {dt4.x, dt4.y, dt4.z, dt4.w};
      float xa[4]  = {xv[j].x, xv[j].y, xv[j].z, xv[j].w};
      float ys[4];
      #pragma unroll
      for (int jj = 0; jj < 4; jj++){
        float dt = dta[jj], x_t = xa[jj];
        float dtx = dt * x_t;
        float y = 0.f;
        #pragma unroll
        for (int n = 0; n < 4; n++){
          float en = fast_exp2(dt * A2[jj][n]);
          h[jj][n] = fmaf(h[jj][n], en, dtx * Ba[n]);
          y = fmaf(h[jj][n], Ca[n], y);
        }
        y = quad_add4(y);                     // sum over 4 state-quads (VALU DPP)
        ys[jj] = fmaf(Dsv[jj], x_t, y);
      }
      if (ng == 0){
        uint2 o;
        o.x = cvtpk_bf16(ys[0], ys[1]);
        o.y = cvtpk_bf16(ys[2], ys[3]);
        *(uint2*)(yb + (size_t)l*D_ + dgl) = o;
      }
    }
  }
}

// ---------- 7a. k_final_a: per-(job, p mod 4) partial pools (256 blocks) ----------
__global__ __launch_bounds__(512) void k_final_a(const void* __restrict__ x,
                                                 const void* __restrict__ og,
                                                 const void* __restrict__ ob,
                                                 const int* __restrict__ topi,
                                                 const unsigned short* __restrict__ ybuf,
                                                 const unsigned short* __restrict__ zbuf,
                                                 float* __restrict__ partial){
  __shared__ float pool[8][512];
  int bf = detect_bf(x);
  int job = blockIdx.x, q = blockIdx.y, t = threadIdx.x;
  int wave = t >> 6, lane = t & 63;
  int e = topi[job];
  int d0 = lane*8;
  const unsigned short* yb = ybuf + (size_t)job*KD_*25088;
  const unsigned short* zb = zbuf + (size_t)job*25088;
  float g[8], o[8];
  {
    f8s gg = ldf8(og, (size_t)e*D_ + d0, bf);
    f8s oo = ldf8(ob, (size_t)e*D_ + d0, bf);
    #pragma unroll
    for (int j = 0; j < 8; j++){ g[j] = gg.v[j]; o[j] = oo.v[j]; }
  }
  float acc[8] = {};
  for (int i = wave; i <= 12; i += 8){
    int p = q + 4*i;
    if (p >= L_) break;
    float v[8] = {};
    #pragma unroll
    for (int k = 0; k < KD_; k++){
      int l = dirmap(k, p);                   // involution
      U4 r; r.u = *(const uint4*)(yb + (size_t)k*25088 + (size_t)l*D_ + d0);
      #pragma unroll
      for (int j = 0; j < 8; j++) v[j] += bf2f(r.us[j]);
    }
    float s = 0.f, ss = 0.f;
    #pragma unroll
    for (int j = 0; j < 8; j++){ s += v[j]; ss += v[j]*v[j]; }
    #pragma unroll
    for (int off = 32; off > 0; off >>= 1){
      s  += __shfl_xor(s,  off, 64);
      ss += __shfl_xor(ss, off, 64);
    }
    float mu = s*(1.f/512.f);
    float var = ss*(1.f/512.f) - mu*mu;
    float rs = rsqrtf(var + 1e-5f);
    U4 zz; zz.u = *(const uint4*)(zb + (size_t)p*D_ + d0);
    #pragma unroll
    for (int j = 0; j < 8; j++){
      float zv = bf2f(zz.us[j]);
      acc[j] += ((v[j]-mu)*rs*g[j] + o[j]) * silu_f(zv);
    }
  }
  #pragma unroll
  for (int j = 0; j < 8; j++) pool[wave][d0+j] = acc[j];
  __syncthreads();
  float pd = pool[0][t]+pool[1][t]+pool[2][t]+pool[3][t]
           + pool[4][t]+pool[5][t]+pool[6][t]+pool[7][t];
  partial[((size_t)(job*4 + q))*512 + t] = pd;
}

// ---------- 7b. k_finmix: combine partials + final LN for both slots -> out ----------
__global__ __launch_bounds__(512) void k_finmix(const void* __restrict__ x,
                                                const void* __restrict__ ngg,
                                                const void* __restrict__ nbb,
                                                const int* __restrict__ topi,
                                                const float* __restrict__ topv,
                                                const float* __restrict__ partial,
                                                void* __restrict__ out){
  __shared__ float red[32];
  int bf = detect_bf(x);
  int b = blockIdx.x, t = threadIdx.x;
  int wave = t >> 6, lane = t & 63;
  int j0 = 2*b, j1 = 2*b + 1;
  int e0 = topi[j0], e1 = topi[j1];
  float g0 = topv[j0], g1 = topv[j1];
  const float* p0 = partial + (size_t)j0*4*512;
  const float* p1 = partial + (size_t)j1*4*512;
  float pd0 = (p0[t] + p0[512+t] + p0[1024+t] + p0[1536+t]) * (1.f/49.f);
  float pd1 = (p1[t] + p1[512+t] + p1[1024+t] + p1[1536+t]) * (1.f/49.f);
  float s0 = pd0, ss0 = pd0*pd0, s1 = pd1, ss1 = pd1*pd1;
  #pragma unroll
  for (int off = 32; off > 0; off >>= 1){
    s0  += __shfl_down(s0,  off, 64);
    ss0 += __shfl_down(ss0, off, 64);
    s1  += __shfl_down(s1,  off, 64);
    ss1 += __shfl_down(ss1, off, 64);
  }
  if (lane == 0){
    red[wave] = s0; red[8+wave] = ss0; red[16+wave] = s1; red[24+wave] = ss1;
  }
  __syncthreads();
  s0 = red[0]+red[1]+red[2]+red[3]+red[4]+red[5]+red[6]+red[7];
  ss0 = red[8]+red[9]+red[10]+red[11]+red[12]+red[13]+red[14]+red[15];
  s1 = red[16]+red[17]+red[18]+red[19]+red[20]+red[21]+red[22]+red[23];
  ss1 = red[24]+red[25]+red[26]+red[27]+red[28]+red[29]+red[30]+red[31];
  float mu0 = s0*(1.f/512.f), var0 = ss0*(1.f/512.f) - mu0*mu0;
  float rs0 = rsqrtf(var0 + 1e-5f);
  float mu1 = s1*(1.f/512.f), var1 = ss1*(1.f/512.f) - mu1*mu1;
  float rs1 = rsqrtf(var1 + 1e-5f);
  float v0 = ((pd0-mu0)*rs0*ldf(ngg, (size_t)e0*D_+t, bf) + ldf(nbb, (size_t)e0*D_+t, bf)) * g0;
  float v1 = ((pd1-mu1)*rs1*ldf(ngg, (size_t)e1*D_+t, bf) + ldf(nbb, (size_t)e1*D_+t, bf)) * g1;
  float v = v0 + v1;
  if (bf) ((unsigned short*)out)[b*D_ + t] = f2bfu(v);
  else    ((float*)out)[b*D_ + t] = v;
}

extern "C" void kernel_launch(void* const* d_in, const int* in_sizes, int n_in,
                              void* d_out, int out_size, void* d_ws, size_t ws_size,
                              hipStream_t stream){
  const void* x    = d_in[0];
  const void* wg   = d_in[1];
  const void* bg   = d_in[2];
  const void* ipw  = d_in[3];
  const void* ipb  = d_in[4];
  const void* cw   = d_in[5];
  const void* cb   = d_in[6];
  const void* xpw  = d_in[7];
  const void* dtw  = d_in[8];
  const void* dtb  = d_in[9];
  const void* alog = d_in[10];
  const void* dss  = d_in[11];
  const void* ogg  = d_in[12];
  const void* obb  = d_in[13];
  const void* ngg  = d_in[14];
  const void* nbb  = d_in[15];
  float* wsf = (float*)d_ws;
  int*   topi  = (int*)d_ws + 16;                          // [16..80)
  float* topv  = wsf + 96;                                 // [96..160)
  float* logits= wsf + 256;                                // 128
  float* xc    = wsf + 16640;                              // 1605632 (6.4MB)
  float* xdbl  = wsf + 1622272;                            // 802816 (3.2MB)
  unsigned short* zbuf = (unsigned short*)(wsf + 2425088); // 1605632 bf16 (3.2MB)
  // ybuf region (12.8MB bf16) is written only by k_scan; until then it hosts:
  //   wtrans [0 .. 2097152)        4MB   written k_prep, read k_inproj
  //   xchi   [2097152 .. 3702784)  3.2MB written k_inproj, read k_xproj
  //   xclo   [3702784 .. 5308416)  3.2MB written k_inproj, read k_xproj
  //   xbf    [5308416 .. 6111232)  1.6MB written k_prep, read k_inproj
  unsigned short* ybuf   = (unsigned short*)(wsf + 3260672);
  unsigned short* wtrans = ybuf;
  unsigned short* xchi   = ybuf + 2097152;
  unsigned short* xclo   = ybuf + 3702784;
  unsigned short* xbf    = ybuf + 5308416;
  float* partial = wsf + 6471936;                          // 64*4*512 = 131072 (~0.5MB)

  k_prep  <<<544, 256, 0, stream>>>(x, ipw, wg, bg, wtrans, xbf, logits);
  k_gate2 <<<1, 128, 0, stream>>>(x, logits, topi, topv, d_out);
  k_inproj_mfma<<<dim3(64,16), 256, 0, stream>>>(x, xbf, wtrans, ipb, cw, cb, topi, zbuf, xc, xchi, xclo);
  k_xproj <<<dim3(16,64), 256, 0, stream>>>(x, xpw, topi, xchi, xclo, xdbl);
  k_scan  <<<dim3(8,64), 256, 0, stream>>>(x, dtw, dtb, alog, dss, topi, xc, xdbl, ybuf);
  k_final_a<<<dim3(64,4), 512, 0, stream>>>(x, ogg, obb, topi, ybuf, zbuf, partial);
  k_finmix<<<32, 512, 0, stream>>>(x, ngg, nbb, topi, topv, partial, d_out);
}

// Round 12
// 189.003 us; speedup vs baseline: 1.2430x; 1.0633x over previous
//
#include <hip/hip_runtime.h>
#include <hip/hip_bf16.h>

#define B_   32
#define D_   512
#define L_   49
#define E_   4
#define KD_  4
#define NS_  16
#define RK_  32
#define JOBS_ 64

typedef short s16x8 __attribute__((ext_vector_type(8)));
typedef float f32x4v __attribute__((ext_vector_type(4)));
union U4 { uint4 u; s16x8 s; unsigned short us[8]; };

// ---------- helpers ----------
__device__ __forceinline__ float bf2f(unsigned short u){
  union{unsigned int i; float f;} v; v.i = ((unsigned int)u)<<16; return v.f;
}
__device__ __forceinline__ float2 bfp(unsigned int u){
  union{unsigned int i; float f;} a, b; a.i = u<<16; b.i = u & 0xffff0000u;
  return make_float2(a.f, b.f);
}
__device__ __forceinline__ unsigned short f2bfu(float f){
  union{float f; unsigned int i;} u; u.f = f;
  unsigned int r = u.i + 0x7fffu + ((u.i >> 16) & 1u);
  return (unsigned short)(r >> 16);
}
__device__ __forceinline__ float silu_f(float x){ return x / (1.f + expf(-x)); }

__device__ __forceinline__ float fast_exp2(float x){
  return __builtin_amdgcn_exp2f(x);
}
__device__ __forceinline__ float quad_add4(float y){
  float t1 = __uint_as_float(__builtin_amdgcn_mov_dpp(__float_as_uint(y), 0xB1, 0xF, 0xF, true));
  y += t1;
  float t2 = __uint_as_float(__builtin_amdgcn_mov_dpp(__float_as_uint(y), 0x4E, 0xF, 0xF, true));
  y += t2;
  return y;
}
__device__ __forceinline__ unsigned cvtpk_bf16(float lo, float hi){
  unsigned r; asm("v_cvt_pk_bf16_f32 %0, %1, %2" : "=v"(r) : "v"(lo), "v"(hi)); return r;
}

// inline dtype detection: wave-ballot over x[0..63] viewed as bf16 (~5 instr).
__device__ __forceinline__ int detect_bf(const void* x){
  unsigned short u = ((const unsigned short*)x)[threadIdx.x & 63];
  int e = (u >> 7) & 0xff;
  unsigned long long m = __ballot(e >= 96 && e < 160);
  return __popcll(m) >= 56;
}

// dtype-agnostic loads: bf=1 -> bf16 (ushort), bf=0 -> float32
__device__ __forceinline__ float ldf(const void* p, size_t i, int bf){
  return bf ? bf2f(((const unsigned short*)p)[i]) : ((const float*)p)[i];
}
struct f8s{ float v[8]; };
__device__ __forceinline__ f8s ldf8(const void* p, size_t i, int bf){
  f8s r;
  if (bf){
    uint4 u = *(const uint4*)((const unsigned short*)p + i);
    float2 x = bfp(u.x), y = bfp(u.y), z = bfp(u.z), w = bfp(u.w);
    r.v[0]=x.x; r.v[1]=x.y; r.v[2]=y.x; r.v[3]=y.y;
    r.v[4]=z.x; r.v[5]=z.y; r.v[6]=w.x; r.v[7]=w.y;
  } else {
    const float4* q = (const float4*)((const float*)p + i);
    float4 a = q[0], b = q[1];
    r.v[0]=a.x; r.v[1]=a.y; r.v[2]=a.z; r.v[3]=a.w;
    r.v[4]=b.x; r.v[5]=b.y; r.v[6]=b.z; r.v[7]=b.w;
  }
  return r;
}
struct f4s{ float v[4]; };
__device__ __forceinline__ f4s ldf4(const void* p, size_t i, int bf){
  f4s r;
  if (bf){
    uint2 u = *(const uint2*)((const unsigned short*)p + i);
    float2 a = bfp(u.x), b = bfp(u.y);
    r.v[0]=a.x; r.v[1]=a.y; r.v[2]=b.x; r.v[3]=b.y;
  } else {
    float4 a = *(const float4*)((const float*)p + i);
    r.v[0]=a.x; r.v[1]=a.y; r.v[2]=a.z; r.v[3]=a.w;
  }
  return r;
}
// load 8 elems as bf16 frag (bf16: direct; fp32: convert)
__device__ __forceinline__ U4 ldbf8(const void* p, size_t i, int bf){
  U4 r;
  if (bf){
    r.u = *(const uint4*)((const unsigned short*)p + i);
  } else {
    const float* q = (const float*)p + i;
    float4 a = *(const float4*)q, b = *(const float4*)(q+4);
    r.u.x = (unsigned)f2bfu(a.x) | ((unsigned)f2bfu(a.y) << 16);
    r.u.y = (unsigned)f2bfu(a.z) | ((unsigned)f2bfu(a.w) << 16);
    r.u.z = (unsigned)f2bfu(b.x) | ((unsigned)f2bfu(b.y) << 16);
    r.u.w = (unsigned)f2bfu(b.z) | ((unsigned)f2bfu(b.w) << 16);
  }
  return r;
}
// split 8 fp32 into hi (truncated bf16) + lo (rounded residual bf16)
__device__ __forceinline__ void split8(const float av[8], U4& hi, U4& lo){
  #pragma unroll
  for (int j = 0; j < 8; j++){
    union{float f; unsigned int i;} u; u.f = av[j];
    unsigned short h = (unsigned short)(u.i >> 16);   // trunc — residual goes to lo
    hi.us[j] = h;
    lo.us[j] = f2bfu(av[j] - bf2f(h));
  }
}

// direction index map: xs[k,d,l] = xc[d, dirmap(k,l)]; all four maps are involutions.
__device__ __forceinline__ int dirmap(int k, int l){
  if (k == 0) return l;
  if (k == 1) return 48 - l;
  if (k == 2) return (l % 7) * 7 + l / 7;
  int l2 = 48 - l; return (l2 % 7) * 7 + l2 / 7;
}

// ---------- 1. k_prep: wtrans (blocks 0..511) + bgate logits + xbf (blocks 512..543) ----------
__global__ __launch_bounds__(256) void k_prep(const void* __restrict__ x,
                                              const void* __restrict__ w,
                                              const void* __restrict__ wg,
                                              const void* __restrict__ bg,
                                              unsigned short* __restrict__ wt,
                                              unsigned short* __restrict__ xbf,
                                              float* __restrict__ logits){
  __shared__ unsigned short tile[64][72];
  __shared__ float red[4][4];
  __shared__ float pool[4][512];
  int bf = detect_bf(x);
  int blk = blockIdx.x;
  int t = threadIdx.x;
  if (blk < 512){
    int e = blk >> 7, cb = (blk >> 3) & 15, db = blk & 7;
    #pragma unroll
    for (int r = 0; r < 4; r++){
      int d  = r*16 + (t>>4);
      int c0 = (t&15)*4;
      size_t g = ((size_t)e*512 + db*64 + d)*1024 + cb*64 + c0;
      if (bf){
        uint2 u = *(const uint2*)((const unsigned short*)w + g);
        tile[c0+0][d] = (unsigned short)(u.x & 0xffffu);
        tile[c0+1][d] = (unsigned short)(u.x >> 16);
        tile[c0+2][d] = (unsigned short)(u.y & 0xffffu);
        tile[c0+3][d] = (unsigned short)(u.y >> 16);
      } else {
        float4 v = *(const float4*)((const float*)w + g);
        tile[c0+0][d] = f2bfu(v.x);
        tile[c0+1][d] = f2bfu(v.y);
        tile[c0+2][d] = f2bfu(v.z);
        tile[c0+3][d] = f2bfu(v.w);
      }
    }
    __syncthreads();
    #pragma unroll
    for (int r = 0; r < 2; r++){
      int o = r*256 + t;
      int c = o >> 3, d0 = (o & 7)*8;
      uint4 v = *(const uint4*)&tile[c][d0];
      *(uint4*)(wt + ((size_t)e*1024 + cb*64 + c)*512 + db*64 + d0) = v;
    }
  } else {
    int b = blk - 512;
    int wave = t >> 6, lane = t & 63;
    int d0 = lane * 8;                        // 64 lanes x 8 d = 512 d's
    float s8[8] = {};
    for (int l = wave; l < L_; l += 4){
      size_t ix = ((size_t)(b*L_ + l))*D_ + d0;
      U4 xb;
      if (bf){
        xb.u = *(const uint4*)((const unsigned short*)x + ix);  // raw bits: bit-identical copy
        float2 a = bfp(xb.u.x), bq = bfp(xb.u.y), c = bfp(xb.u.z), dq = bfp(xb.u.w);
        s8[0] += a.x;  s8[1] += a.y;  s8[2] += bq.x; s8[3] += bq.y;
        s8[4] += c.x;  s8[5] += c.y;  s8[6] += dq.x; s8[7] += dq.y;
      } else {
        const float* q = (const float*)x + ix;
        float4 f0 = *(const float4*)q, f1 = *(const float4*)(q+4);
        float av[8] = {f0.x,f0.y,f0.z,f0.w, f1.x,f1.y,f1.z,f1.w};
        #pragma unroll
        for (int j = 0; j < 8; j++){ xb.us[j] = f2bfu(av[j]); s8[j] += av[j]; }
      }
      *(uint4*)(xbf + ix) = xb.u;
    }
    #pragma unroll
    for (int j = 0; j < 8; j++) pool[wave][d0+j] = s8[j];
    __syncthreads();
    float p[4] = {0.f, 0.f, 0.f, 0.f};
    #pragma unroll
    for (int rep = 0; rep < 2; rep++){
      int d = t + rep*256;
      float s = pool[0][d] + pool[1][d] + pool[2][d] + pool[3][d];
      float xfd = s * (1.f/49.f);
      #pragma unroll
      for (int e = 0; e < 4; e++) p[e] = fmaf(xfd, ldf(wg, (size_t)d*E_ + e, bf), p[e]);
    }
    #pragma unroll
    for (int off = 32; off > 0; off >>= 1){
      #pragma unroll
      for (int e = 0; e < 4; e++) p[e] += __shfl_down(p[e], off, 64);
    }
    if (lane == 0){
      #pragma unroll
      for (int e = 0; e < 4; e++) red[wave][e] = p[e];
    }
    __syncthreads();
    if (t < 4)
      logits[b*4 + t] = red[0][t]+red[1][t]+red[2][t]+red[3][t] + ldf(bg, t, bf);
  }
}

// ---------- 2. k_gate2: softmax/top-k/aux from precomputed logits (1 block) ----------
__global__ __launch_bounds__(128) void k_gate2(const void* __restrict__ x,
                                               const float* __restrict__ logits,
                                               int* __restrict__ topi, float* __restrict__ topv,
                                               void* __restrict__ out){
  __shared__ float raw[B_*E_];
  __shared__ int   sel[B_];
  __shared__ float den[E_], auxp[E_];
  int bf = detect_bf(x);
  int t = threadIdx.x;
  if (t < B_){
    float l0=logits[t*4+0], l1=logits[t*4+1], l2=logits[t*4+2], l3=logits[t*4+3];
    float m = fmaxf(fmaxf(l0,l1), fmaxf(l2,l3));
    float e0=expf(l0-m), e1=expf(l1-m), e2=expf(l2-m), e3=expf(l3-m);
    float s = e0+e1+e2+e3;
    float r[4] = {e0/s, e1/s, e2/s, e3/s};
    int i1 = 0; float v1 = r[0];
    for (int e = 1; e < 4; e++) if (r[e] > v1){ v1 = r[e]; i1 = e; }
    int i2 = -1; float v2 = -1.f;
    for (int e = 0; e < 4; e++){ if (e == i1) continue; if (r[e] > v2){ v2 = r[e]; i2 = e; } }
    if (i1 < 0 || i1 > 3) i1 = 0;
    if (i2 < 0 || i2 > 3) i2 = (i1 + 1) & 3;
    sel[t] = (1<<i1) | (1<<i2);
    for (int e = 0; e < 4; e++) raw[t*4+e] = r[e];
  }
  __syncthreads();
  if (t < E_){
    float dn = 0.f, imp = 0.f, ld = 0.f;
    for (int b = 0; b < B_; b++){
      float r = raw[b*4+t];
      int bit = (sel[b] >> t) & 1;
      if (bit) dn += r;
      imp += r; ld += (float)bit;
    }
    den[t] = dn + 1e-6f;
    imp *= (1.f/B_); ld *= (1.f/B_);
    float df = ld - imp; auxp[t] = df*df;
  }
  __syncthreads();
  if (t == 0){
    float a = 0.01f * 0.25f * (auxp[0]+auxp[1]+auxp[2]+auxp[3]);
    if (bf) ((unsigned short*)out)[16384] = f2bfu(a);
    else    ((float*)out)[16384] = a;
  }
  if (t < B_){
    float gs[4];
    for (int e = 0; e < 4; e++){
      int bit = (sel[t] >> e) & 1;
      gs[e] = bit ? raw[t*4+e] * 40.f / den[e] : 0.f;   // capacity = int(1.25*32) = 40
    }
    int i1 = 0; float v1 = gs[0];
    for (int e = 1; e < 4; e++) if (gs[e] > v1){ v1 = gs[e]; i1 = e; }
    int i2 = -1; float v2 = -1e30f;
    for (int e = 0; e < 4; e++){ if (e == i1) continue; if (gs[e] > v2){ v2 = gs[e]; i2 = e; } }
    if (i1 < 0 || i1 > 3) i1 = 0;
    if (i2 < 0 || i2 > 3) i2 = (i1 + 1) & 3;
    topi[t*2+0] = i1; topv[t*2+0] = v1;
    topi[t*2+1] = i2; topv[t*2+1] = v2;
  }
}

// ---------- 3. in_proj v4: double-buffered LDS staging of B (R11-proven) ----------
__global__ __launch_bounds__(256, 4) void k_inproj_mfma(const void* __restrict__ x,
                                                     const unsigned short* __restrict__ xbf,
                                                     const unsigned short* __restrict__ wt,
                                                     const void* __restrict__ bias,
                                                     const void* __restrict__ cw,
                                                     const void* __restrict__ cb,
                                                     const int* __restrict__ topi,
                                                     unsigned short* __restrict__ zbuf,
                                                     float* __restrict__ xc,
                                                     unsigned short* __restrict__ xchi,
                                                     unsigned short* __restrict__ xclo){
  __shared__ unsigned short smem[2*4096];     // 2 bufs x [64 col][64 k] bf16 = 16KB
  float* xzt = (float*)smem;                  // [49][68] f32 alias for conv (13.3KB)
  int bf = detect_bf(x);
  int job = blockIdx.x, nt = blockIdx.y;
  int b = job >> 1;
  int e = topi[job];
  int t = threadIdx.x;
  int wave = t >> 6, lane = t & 63;
  int l16 = lane & 15, quad = lane >> 4;
  int arow = wave*16 + l16; if (arow > 48) arow = 48;   // pad rows duplicate row 48
  size_t abase = ((size_t)(b*L_ + arow))*D_;
  int ct = nt*64;
  const unsigned short* wsrc = wt + (size_t)(e*1024 + ct)*512;
  f32x4v acc[4] = {};
  // prologue: stage step 0 into buf0; prefetch A frags for step 0
  #pragma unroll
  for (int cc = 0; cc < 2; cc++){
    int c = t + cc*256;
    int col = c >> 3, ko8 = c & 7;
    uint4 v = *(const uint4*)(wsrc + (size_t)col*512 + ko8*8);
    *(uint4*)(smem + col*64 + ((ko8 ^ (col & 7))*8)) = v;
  }
  U4 aA, aB;
  aA.u = *(const uint4*)(xbf + abase + quad*8);
  aB.u = *(const uint4*)(xbf + abase + 32 + quad*8);
  __syncthreads();
  for (int s = 0; s < 8; s++){
    unsigned short* cur = smem + (s & 1)*4096;
    U4 nA, nB;
    if (s < 7){
      unsigned short* nxt = smem + ((s+1) & 1)*4096;
      int k0n = (s+1)*64;
      #pragma unroll
      for (int cc = 0; cc < 2; cc++){
        int c = t + cc*256;
        int col = c >> 3, ko8 = c & 7;
        uint4 v = *(const uint4*)(wsrc + (size_t)col*512 + k0n + ko8*8);
        *(uint4*)(nxt + col*64 + ((ko8 ^ (col & 7))*8)) = v;
      }
      nA.u = *(const uint4*)(xbf + abase + k0n + quad*8);
      nB.u = *(const uint4*)(xbf + abase + k0n + 32 + quad*8);
    }
    // compute step s from cur (ks=0 -> aA, ks=1 -> aB); MFMA order == v2
    {
      int ko8 = quad;                         // ks=0
      #pragma unroll
      for (int ss = 0; ss < 4; ss++){
        int col = ss*16 + l16;
        U4 bb; bb.u = *(const uint4*)(cur + col*64 + ((ko8 ^ (col & 7))*8));
        acc[ss] = __builtin_amdgcn_mfma_f32_16x16x32_bf16(aA.s, bb.s, acc[ss], 0, 0, 0);
      }
      ko8 = 4 + quad;                         // ks=1
      #pragma unroll
      for (int ss = 0; ss < 4; ss++){
        int col = ss*16 + l16;
        U4 bb; bb.u = *(const uint4*)(cur + col*64 + ((ko8 ^ (col & 7))*8));
        acc[ss] = __builtin_amdgcn_mfma_f32_16x16x32_bf16(aB.s, bb.s, acc[ss], 0, 0, 0);
      }
    }
    aA = nA; aB = nB;
    __syncthreads();
  }
  int rb = wave*16 + quad*4;
  if (nt >= 8){
    #pragma unroll
    for (int s = 0; s < 4; s++){
      int c = ct + s*16 + l16;
      float bv = ldf(bias, (size_t)e*1024 + c, bf);
      #pragma unroll
      for (int r = 0; r < 4; r++){
        int row = rb + r;
        if (row < L_)
          zbuf[(size_t)job*25088 + row*D_ + (c - 512)] = f2bfu(acc[s][r] + bv);
      }
    }
    return;
  }
  // xz half: stage to LDS (aliases staging bufs; safe after final barrier), then conv
  #pragma unroll
  for (int s = 0; s < 4; s++){
    int cl = s*16 + l16;
    float bv = ldf(bias, (size_t)e*1024 + ct + cl, bf);
    #pragma unroll
    for (int r = 0; r < 4; r++){
      int row = rb + r;
      if (row < L_) xzt[row*68 + cl] = acc[s][r] + bv;
    }
  }
  __syncthreads();
  int c = t & 63, pg = t >> 6;                // 64 channels x 4 p-groups
  int dch = ct + c;
  float wv[9];
  #pragma unroll
  for (int j = 0; j < 9; j++) wv[j] = ldf(cw, ((size_t)(e*D_ + dch))*9 + j, bf);
  float cbv = ldf(cb, (size_t)e*D_ + dch, bf);
  for (int p = pg; p < L_; p += 4){
    int h = p / 7, w = p % 7;
    float a2 = cbv;
    #pragma unroll
    for (int dy = 0; dy < 3; dy++){
      int hh = h + dy - 1; if (hh < 0 || hh >= 7) continue;
      #pragma unroll
      for (int dx = 0; dx < 3; dx++){
        int ww = w + dx - 1; if (ww < 0 || ww >= 7) continue;
        a2 = fmaf(xzt[(hh*7+ww)*68 + c], wv[dy*3+dx], a2);
      }
    }
    float sv = a2 * (1.f/(1.f+expf(-a2)));
    size_t oix = (size_t)job*25088 + (size_t)p*D_ + dch;
    xc[oix] = sv;
    unsigned int ui = __float_as_uint(sv);
    unsigned short hh2 = (unsigned short)(ui >> 16);    // trunc
    xchi[oix] = hh2;
    xclo[oix] = f2bfu(sv - bf2f(hh2));
  }
}

// ---------- 5. x_proj v6: same staging recipe (dbuf LDS B, reg-prefetched A hi/lo) ----------
// Same latency diagnosis as k_inproj pre-R11: 16 rolled iters x 3 serialized 16B
// loads. Now: 512 cooperative B-loads/K-step into swizzled LDS, A one step ahead.
// MFMA order identical to the old loop (per 32-k: hi then lo) -> bit-identical.
__global__ __launch_bounds__(256, 4) void k_xproj(const void* __restrict__ x,
                                               const void* __restrict__ xpw,
                                               const int* __restrict__ topi,
                                               const unsigned short* __restrict__ xchi,
                                               const unsigned short* __restrict__ xclo,
                                               float* __restrict__ xdbl){
  __shared__ unsigned short smem[2*4096];     // 2 bufs x [64 col][64 k] bf16 = 16KB
  int bf = detect_bf(x);
  int kq = blockIdx.x, job = blockIdx.y;
  int k = kq & 3, q = kq >> 2;
  int t = threadIdx.x;
  int wave = t >> 6, lane = t & 63;
  int l16 = lane & 15, quad = lane >> 4;
  int e = topi[job];
  int arow = q*16 + l16; if (arow > 48) arow = 48;      // q=3 pad rows dup row 48
  int m = dirmap(k, arow);
  const unsigned short* ahp = xchi + (size_t)job*25088 + (size_t)m*D_;
  const unsigned short* alp = xclo + (size_t)job*25088 + (size_t)m*D_;
  size_t bsrc = ((size_t)(e*KD_+k))*64*512;             // element base into xpw
  int col16 = wave*16 + l16;                            // this lane's B row
  f32x4v acc = {};
  // prologue: stage step 0; prefetch A frags (hi/lo x 2 sub-steps)
  #pragma unroll
  for (int cc = 0; cc < 2; cc++){
    int c = t + cc*256;
    int col = c >> 3, ko8 = c & 7;
    U4 v = ldbf8(xpw, bsrc + (size_t)col*512 + ko8*8, bf);
    *(uint4*)(smem + col*64 + ((ko8 ^ (col & 7))*8)) = v.u;
  }
  U4 hA, hB, lA, lB;
  hA.u = *(const uint4*)(ahp + quad*8);
  lA.u = *(const uint4*)(alp + quad*8);
  hB.u = *(const uint4*)(ahp + 32 + quad*8);
  lB.u = *(const uint4*)(alp + 32 + quad*8);
  __syncthreads();
  for (int s = 0; s < 8; s++){
    unsigned short* cur = smem + (s & 1)*4096;
    U4 nhA, nhB, nlA, nlB;
    if (s < 7){
      unsigned short* nxt = smem + ((s+1) & 1)*4096;
      int k0n = (s+1)*64;
      #pragma unroll
      for (int cc = 0; cc < 2; cc++){
        int c = t + cc*256;
        int col = c >> 3, ko8 = c & 7;
        U4 v = ldbf8(xpw, bsrc + (size_t)col*512 + k0n + ko8*8, bf);
        *(uint4*)(nxt + col*64 + ((ko8 ^ (col & 7))*8)) = v.u;
      }
      nhA.u = *(const uint4*)(ahp + k0n + quad*8);
      nlA.u = *(const uint4*)(alp + k0n + quad*8);
      nhB.u = *(const uint4*)(ahp + k0n + 32 + quad*8);
      nlB.u = *(const uint4*)(alp + k0n + 32 + quad*8);
    }
    {
      int ko8 = quad;                         // ks=0 (orig k0 = s*64)
      U4 bb;  bb.u  = *(const uint4*)(cur + col16*64 + ((ko8 ^ (col16 & 7))*8));
      acc = __builtin_amdgcn_mfma_f32_16x16x32_bf16(hA.s, bb.s, acc, 0, 0, 0);
      acc = __builtin_amdgcn_mfma_f32_16x16x32_bf16(lA.s, bb.s, acc, 0, 0, 0);
      ko8 = 4 + quad;                         // ks=1 (orig k0 = s*64+32)
      U4 bb2; bb2.u = *(const uint4*)(cur + col16*64 + ((ko8 ^ (col16 & 7))*8));
      acc = __builtin_amdgcn_mfma_f32_16x16x32_bf16(hB.s, bb2.s, acc, 0, 0, 0);
      acc = __builtin_amdgcn_mfma_f32_16x16x32_bf16(lB.s, bb2.s, acc, 0, 0, 0);
    }
    hA = nhA; hB = nhB; lA = nlA; lB = nlB;
    __syncthreads();
  }
  float* outb = xdbl + ((size_t)(job*KD_+k))*3136;
  int rb = q*16 + quad*4;
  int c = wave*16 + l16;
  #pragma unroll
  for (int r = 0; r < 4; r++){
    int row = rb + r;
    if (row < L_) outb[row*64 + c] = acc[r];
  }
}

// ---------- 6. k_scan v9b: v8 structure, instruction-trimmed hot loop (builtin-safe) ----------
// CONFIRMED R6: k_scan is CU-issue-bound; instruction trim took it 55 -> <43us.
__global__ __launch_bounds__(256, 2) void k_scan(const void* __restrict__ x,
                                              const void* __restrict__ dtw,
                                              const void* __restrict__ dtb_,
                                              const void* __restrict__ alog,
                                              const void* __restrict__ ds_,
                                              const int* __restrict__ topi,
                                              const float* __restrict__ xc,
                                              const float* __restrict__ xdbl,
                                              unsigned short* __restrict__ ybuf){
  int bf = detect_bf(x);
  int kz = blockIdx.x, job = blockIdx.y;
  int k = kz & 3, dz2 = kz >> 2;              // dz2 = d-half (256 d's per block)
  int t = threadIdx.x;
  int e = topi[job];
  int ek = e*KD_ + k;
  __shared__ float bc[49*32];                 // [l][B(16)|C(16)]
  __shared__ float dtl[49*260];               // dt[l][d_local 0..255], stride 260
  const float* xdb = xdbl + ((size_t)(job*KD_+k))*3136;
  // stage B/C columns (xdbl cols 32..63) -> bc
  {
    const float4* src4 = (const float4*)xdb;
    for (int i = t; i < 392; i += 256){
      int row = i >> 3, c = i & 7;
      ((float4*)bc)[row*8 + c] = src4[row*16 + 8 + c];
    }
  }
  int w = t >> 6, lane = t & 63;
  // ---- phase 1: dt GEMM; wave w computes its own 64-d slice (cols w*64..w*64+63) ----
  {
    int l16 = lane & 15, quad4 = lane >> 4;
    U4 Bv[4];
    #pragma unroll
    for (int nt = 0; nt < 4; nt++){
      int d = dz2*256 + w*64 + nt*16 + l16;
      Bv[nt] = ldbf8(dtw, ((size_t)ek*D_ + d)*RK_ + quad4*8, bf);
    }
    f32x4v acc[4][4] = {};
    #pragma unroll
    for (int rt = 0; rt < 4; rt++){
      int arow = rt*16 + l16; if (arow > 48) arow = 48;
      const float* ap = xdb + arow*64 + quad4*8;        // dt_raw cols 0..31
      float4 f0 = *(const float4*)ap, f1 = *(const float4*)(ap+4);
      float av[8] = {f0.x,f0.y,f0.z,f0.w, f1.x,f1.y,f1.z,f1.w};
      U4 Ahi, Alo;
      split8(av, Ahi, Alo);
      #pragma unroll
      for (int nt = 0; nt < 4; nt++){
        acc[rt][nt] = __builtin_amdgcn_mfma_f32_16x16x32_bf16(Ahi.s, Bv[nt].s, acc[rt][nt], 0, 0, 0);
        acc[rt][nt] = __builtin_amdgcn_mfma_f32_16x16x32_bf16(Alo.s, Bv[nt].s, acc[rt][nt], 0, 0, 0);
      }
    }
    #pragma unroll
    for (int nt = 0; nt < 4; nt++){
      int d = dz2*256 + w*64 + nt*16 + l16;
      float bias = ldf(dtb_, (size_t)ek*D_ + d, bf);
      int dloc = w*64 + nt*16 + l16;
      #pragma unroll
      for (int rt = 0; rt < 4; rt++){
        #pragma unroll
        for (int r = 0; r < 4; r++){
          int l = rt*16 + quad4*4 + r;
          if (l < L_){
            float v = acc[rt][nt][r] + bias;
            dtl[l*260 + dloc] = fmaxf(v, 0.f) + __logf(1.f + __expf(-fabsf(v)));
          }
        }
      }
    }
  }
  // ---- phase 2 params: thread owns 4 consecutive d's (quad q) x 4 states (ng) ----
  int q4 = (lane >> 2) * 4;                   // 0,4,..,60 within wave's 64-d slice
  int ng = lane & 3;                          // state quad: states ng*4..ng*4+3
  int dgl = dz2*256 + w*64 + q4;              // global d of first owned d
  float A2[4][4], Dsv[4];
  #pragma unroll
  for (int jj = 0; jj < 4; jj++){
    int dj = dgl + jj;
    f4s ar = ldf4(alog, ((size_t)ek*D_ + dj)*NS_ + ng*4, bf);
    #pragma unroll
    for (int n = 0; n < 4; n++) A2[jj][n] = -expf(ar.v[n]) * 1.44269504f;
    Dsv[jj] = ldf(ds_, (size_t)ek*D_ + dj, bf);
  }
  __syncthreads();
  // ---- phase 2: scan, 7 chunks of 7 with x_t batch prefetch (L2-hot xc) ----
  float h[4][4];
  #pragma unroll
  for (int jj = 0; jj < 4; jj++)
    #pragma unroll
    for (int n = 0; n < 4; n++) h[jj][n] = 0.f;
  const float* xcb = xc + (size_t)job*25088;
  unsigned short* yb = ybuf + ((size_t)(job*KD_ + k))*25088;
  int dtbase = w*64 + q4;
  for (int c0 = 0; c0 < 49; c0 += 7){
    float4 xv[7];
    #pragma unroll
    for (int j = 0; j < 7; j++){
      int m = dirmap(k, c0 + j);
      xv[j] = *(const float4*)(xcb + (size_t)m*D_ + dgl);
    }
    #pragma unroll
    for (int j = 0; j < 7; j++){
      int l = c0 + j;
      float4 dt4 = *(const float4*)&dtl[l*260 + dtbase];
      float4 B4 = *(const float4*)&bc[l*32 + ng*4];
      float4 C4 = *(const float4*)&bc[l*32 + 16 + ng*4];
      float Ba[4] = {B4.x, B4.y, B4.z, B4.w};
      float Ca[4] = {C4.x, C4.y, C4.z, C4.w};
      float dta[4] = {dt4.x, dt4.y, dt4.z, dt4.w};
      float xa[4]  = {xv[j].x, xv[j].y, xv[j].z, xv[j].w};
      float ys[4];
      #pragma unroll
      for (int jj = 0; jj < 4; jj++){
        float dt = dta[jj], x_t = xa[jj];
        float dtx = dt * x_t;
        float y = 0.f;
        #pragma unroll
        for (int n = 0; n < 4; n++){
          float en = fast_exp2(dt * A2[jj][n]);
          h[jj][n] = fmaf(h[jj][n], en, dtx * Ba[n]);
          y = fmaf(h[jj][n], Ca[n], y);
        }
        y = quad_add4(y);                     // sum over 4 state-quads (VALU DPP)
        ys[jj] = fmaf(Dsv[jj], x_t, y);
      }
      if (ng == 0){
        uint2 o;
        o.x = cvtpk_bf16(ys[0], ys[1]);
        o.y = cvtpk_bf16(ys[2], ys[3]);
        *(uint2*)(yb + (size_t)l*D_ + dgl) = o;
      }
    }
  }
}

// ---------- 7a. k_final_a: per-(job, p mod 4) partial pools (256 blocks) ----------
__global__ __launch_bounds__(512) void k_final_a(const void* __restrict__ x,
                                                 const void* __restrict__ og,
                                                 const void* __restrict__ ob,
                                                 const int* __restrict__ topi,
                                                 const unsigned short* __restrict__ ybuf,
                                                 const unsigned short* __restrict__ zbuf,
                                                 float* __restrict__ partial){
  __shared__ float pool[8][512];
  int bf = detect_bf(x);
  int job = blockIdx.x, q = blockIdx.y, t = threadIdx.x;
  int wave = t >> 6, lane = t & 63;
  int e = topi[job];
  int d0 = lane*8;
  const unsigned short* yb = ybuf + (size_t)job*KD_*25088;
  const unsigned short* zb = zbuf + (size_t)job*25088;
  float g[8], o[8];
  {
    f8s gg = ldf8(og, (size_t)e*D_ + d0, bf);
    f8s oo = ldf8(ob, (size_t)e*D_ + d0, bf);
    #pragma unroll
    for (int j = 0; j < 8; j++){ g[j] = gg.v[j]; o[j] = oo.v[j]; }
  }
  float acc[8] = {};
  for (int i = wave; i <= 12; i += 8){
    int p = q + 4*i;
    if (p >= L_) break;
    float v[8] = {};
    #pragma unroll
    for (int k = 0; k < KD_; k++){
      int l = dirmap(k, p);                   // involution
      U4 r; r.u = *(const uint4*)(yb + (size_t)k*25088 + (size_t)l*D_ + d0);
      #pragma unroll
      for (int j = 0; j < 8; j++) v[j] += bf2f(r.us[j]);
    }
    float s = 0.f, ss = 0.f;
    #pragma unroll
    for (int j = 0; j < 8; j++){ s += v[j]; ss += v[j]*v[j]; }
    #pragma unroll
    for (int off = 32; off > 0; off >>= 1){
      s  += __shfl_xor(s,  off, 64);
      ss += __shfl_xor(ss, off, 64);
    }
    float mu = s*(1.f/512.f);
    float var = ss*(1.f/512.f) - mu*mu;
    float rs = rsqrtf(var + 1e-5f);
    U4 zz; zz.u = *(const uint4*)(zb + (size_t)p*D_ + d0);
    #pragma unroll
    for (int j = 0; j < 8; j++){
      float zv = bf2f(zz.us[j]);
      acc[j] += ((v[j]-mu)*rs*g[j] + o[j]) * silu_f(zv);
    }
  }
  #pragma unroll
  for (int j = 0; j < 8; j++) pool[wave][d0+j] = acc[j];
  __syncthreads();
  float pd = pool[0][t]+pool[1][t]+pool[2][t]+pool[3][t]
           + pool[4][t]+pool[5][t]+pool[6][t]+pool[7][t];
  partial[((size_t)(job*4 + q))*512 + t] = pd;
}

// ---------- 7b. k_finmix: combine partials + final LN for both slots -> out ----------
__global__ __launch_bounds__(512) void k_finmix(const void* __restrict__ x,
                                                const void* __restrict__ ngg,
                                                const void* __restrict__ nbb,
                                                const int* __restrict__ topi,
                                                const float* __restrict__ topv,
                                                const float* __restrict__ partial,
                                                void* __restrict__ out){
  __shared__ float red[32];
  int bf = detect_bf(x);
  int b = blockIdx.x, t = threadIdx.x;
  int wave = t >> 6, lane = t & 63;
  int j0 = 2*b, j1 = 2*b + 1;
  int e0 = topi[j0], e1 = topi[j1];
  float g0 = topv[j0], g1 = topv[j1];
  const float* p0 = partial + (size_t)j0*4*512;
  const float* p1 = partial + (size_t)j1*4*512;
  float pd0 = (p0[t] + p0[512+t] + p0[1024+t] + p0[1536+t]) * (1.f/49.f);
  float pd1 = (p1[t] + p1[512+t] + p1[1024+t] + p1[1536+t]) * (1.f/49.f);
  float s0 = pd0, ss0 = pd0*pd0, s1 = pd1, ss1 = pd1*pd1;
  #pragma unroll
  for (int off = 32; off > 0; off >>= 1){
    s0  += __shfl_down(s0,  off, 64);
    ss0 += __shfl_down(ss0, off, 64);
    s1  += __shfl_down(s1,  off, 64);
    ss1 += __shfl_down(ss1, off, 64);
  }
  if (lane == 0){
    red[wave] = s0; red[8+wave] = ss0; red[16+wave] = s1; red[24+wave] = ss1;
  }
  __syncthreads();
  s0 = red[0]+red[1]+red[2]+red[3]+red[4]+red[5]+red[6]+red[7];
  ss0 = red[8]+red[9]+red[10]+red[11]+red[12]+red[13]+red[14]+red[15];
  s1 = red[16]+red[17]+red[18]+red[19]+red[20]+red[21]+red[22]+red[23];
  ss1 = red[24]+red[25]+red[26]+red[27]+red[28]+red[29]+red[30]+red[31];
  float mu0 = s0*(1.f/512.f), var0 = ss0*(1.f/512.f) - mu0*mu0;
  float rs0 = rsqrtf(var0 + 1e-5f);
  float mu1 = s1*(1.f/512.f), var1 = ss1*(1.f/512.f) - mu1*mu1;
  float rs1 = rsqrtf(var1 + 1e-5f);
  float v0 = ((pd0-mu0)*rs0*ldf(ngg, (size_t)e0*D_+t, bf) + ldf(nbb, (size_t)e0*D_+t, bf)) * g0;
  float v1 = ((pd1-mu1)*rs1*ldf(ngg, (size_t)e1*D_+t, bf) + ldf(nbb, (size_t)e1*D_+t, bf)) * g1;
  float v = v0 + v1;
  if (bf) ((unsigned short*)out)[b*D_ + t] = f2bfu(v);
  else    ((float*)out)[b*D_ + t] = v;
}

extern "C" void kernel_launch(void* const* d_in, const int* in_sizes, int n_in,
                              void* d_out, int out_size, void* d_ws, size_t ws_size,
                              hipStream_t stream){
  const void* x    = d_in[0];
  const void* wg   = d_in[1];
  const void* bg   = d_in[2];
  const void* ipw  = d_in[3];
  const void* ipb  = d_in[4];
  const void* cw   = d_in[5];
  const void* cb   = d_in[6];
  const void* xpw  = d_in[7];
  const void* dtw  = d_in[8];
  const void* dtb  = d_in[9];
  const void* alog = d_in[10];
  const void* dss  = d_in[11];
  const void* ogg  = d_in[12];
  const void* obb  = d_in[13];
  const void* ngg  = d_in[14];
  const void* nbb  = d_in[15];
  float* wsf = (float*)d_ws;
  int*   topi  = (int*)d_ws + 16;                          // [16..80)
  float* topv  = wsf + 96;                                 // [96..160)
  float* logits= wsf + 256;                                // 128
  float* xc    = wsf + 16640;                              // 1605632 (6.4MB)
  float* xdbl  = wsf + 1622272;                            // 802816 (3.2MB)
  unsigned short* zbuf = (unsigned short*)(wsf + 2425088); // 1605632 bf16 (3.2MB)
  // ybuf region (12.8MB bf16) is written only by k_scan; until then it hosts:
  //   wtrans [0 .. 2097152)        4MB   written k_prep, read k_inproj
  //   xchi   [2097152 .. 3702784)  3.2MB written k_inproj, read k_xproj
  //   xclo   [3702784 .. 5308416)  3.2MB written k_inproj, read k_xproj
  //   xbf    [5308416 .. 6111232)  1.6MB written k_prep, read k_inproj
  unsigned short* ybuf   = (unsigned short*)(wsf + 3260672);
  unsigned short* wtrans = ybuf;
  unsigned short* xchi   = ybuf + 2097152;
  unsigned short* xclo   = ybuf + 3702784;
  unsigned short* xbf    = ybuf + 5308416;
  float* partial = wsf + 6471936;                          // 64*4*512 = 131072 (~0.5MB)

  k_prep  <<<544, 256, 0, stream>>>(x, ipw, wg, bg, wtrans, xbf, logits);
  k_gate2 <<<1, 128, 0, stream>>>(x, logits, topi, topv, d_out);
  k_inproj_mfma<<<dim3(64,16), 256, 0, stream>>>(x, xbf, wtrans, ipb, cw, cb, topi, zbuf, xc, xchi, xclo);
  k_xproj <<<dim3(16,64), 256, 0, stream>>>(x, xpw, topi, xchi, xclo, xdbl);
  k_scan  <<<dim3(8,64), 256, 0, stream>>>(x, dtw, dtb, alog, dss, topi, xc, xdbl, ybuf);
  k_final_a<<<dim3(64,4), 512, 0, stream>>>(x, ogg, obb, topi, ybuf, zbuf, partial);
  k_finmix<<<32, 512, 0, stream>>>(x, ngg, nbb, topi, topv, partial, d_out);
}